// Round 2
// baseline (4516.553 us; speedup 1.0000x reference)
//
#include <hip/hip_runtime.h>
#include <hip/hip_bf16.h>

constexpr int LYR  = 4;
constexpr int DM   = 384;
constexpr int HIDN = 1536;
constexpr int NHEAD = 6;
constexpr int HDIM = 64;
constexpr int NEXP = 8;
constexpr int SEQ  = 197;
constexpr int BATCH = 8;
constexpr int TOK  = BATCH * SEQ;   // 1576
constexpr int NCLS = 1000;
constexpr int CAPE = TOK;           // max pairs per expert
constexpr float EPSLN = 1e-5f;

// ---------------- threefry2x32 (JAX-compatible) ----------------
__host__ __device__ inline void tf2x32(unsigned k0, unsigned k1, unsigned x0, unsigned x1,
                                       unsigned& y0, unsigned& y1) {
  unsigned ks2 = k0 ^ k1 ^ 0x1BD11BDAu;
  unsigned v0 = x0 + k0, v1 = x1 + k1;
#define TFR(r) { v0 += v1; v1 = (v1 << (r)) | (v1 >> (32 - (r))); v1 ^= v0; }
  TFR(13) TFR(15) TFR(26) TFR(6)
  v0 += k1;  v1 += ks2 + 1u;
  TFR(17) TFR(29) TFR(16) TFR(24)
  v0 += ks2; v1 += k0 + 2u;
  TFR(13) TFR(15) TFR(26) TFR(6)
  v0 += k0;  v1 += k1 + 3u;
  TFR(17) TFR(29) TFR(16) TFR(24)
  v0 += k1;  v1 += ks2 + 4u;
  TFR(13) TFR(15) TFR(26) TFR(6)
  v0 += ks2; v1 += k0 + 5u;
#undef TFR
  y0 = v0; y1 = v1;
}

// XLA ErfInv32 (Giles) — matches jax.lax.erf_inv for f32
__device__ inline float erfinv32(float x) {
  float w = -log1pf(-x * x);
  float p;
  if (w < 5.f) {
    w -= 2.5f;
    p = 2.81022636e-08f;
    p = fmaf(p, w, 3.43273939e-07f);
    p = fmaf(p, w, -3.5233877e-06f);
    p = fmaf(p, w, -4.39150654e-06f);
    p = fmaf(p, w, 0.00021858087f);
    p = fmaf(p, w, -0.00125372503f);
    p = fmaf(p, w, -0.00417768164f);
    p = fmaf(p, w, 0.246640727f);
    p = fmaf(p, w, 1.50140941f);
  } else {
    w = sqrtf(w) - 3.f;
    p = -0.000200214257f;
    p = fmaf(p, w, 0.000100950558f);
    p = fmaf(p, w, 0.00134934322f);
    p = fmaf(p, w, -0.00367342844f);
    p = fmaf(p, w, 0.00573950773f);
    p = fmaf(p, w, -0.0076224613f);
    p = fmaf(p, w, 0.00943887047f);
    p = fmaf(p, w, 1.00167406f);
    p = fmaf(p, w, 2.83297682f);
  }
  return p * x;
}

__device__ inline float gelu_f(float x) {
  return 0.5f * x * (1.f + erff(x * 0.70710678118654752f));
}

// ---------------- patch embed: tiles of 8 patches ----------------
__global__ void patch_embed_kernel(const float* __restrict__ x, const float* __restrict__ pw,
                                   const float* __restrict__ pb, const float* __restrict__ pos,
                                   float* __restrict__ t) {
  const int PTILES = 25;  // ceil(196/8)
  int b = blockIdx.x / PTILES, tile = blockIdx.x % PTILES;
  int n0 = tile * 8;
  int rows = min(8, 196 - n0);
  __shared__ float xs[8][768];
  int tid = threadIdx.x;  // 384 threads
  for (int i = tid; i < 8 * 768; i += 384) {
    int r = i / 768, f = i - r * 768;
    float v = 0.f;
    if (r < rows) {
      int n = n0 + r;
      int c = f >> 8, py = (f >> 4) & 15, px = f & 15;
      int hp = n / 14, wp = n - hp * 14;
      v = x[((b * 3 + c) * 224 + hp * 16 + py) * 224 + wp * 16 + px];
    }
    xs[r][f] = v;
  }
  __syncthreads();
  float acc[8];
#pragma unroll
  for (int r = 0; r < 8; r++) acc[r] = 0.f;
  for (int k = 0; k < 768; k++) {
    float w = pw[k * DM + tid];
#pragma unroll
    for (int r = 0; r < 8; r++) acc[r] += xs[r][k] * w;
  }
  float bb = pb[tid];
  for (int r = 0; r < rows; r++) {
    int token = 1 + n0 + r;
    t[(b * SEQ + token) * DM + tid] = acc[r] + bb + pos[token * DM + tid];
  }
}

__global__ void cls_pos_kernel(const float* __restrict__ cls, const float* __restrict__ pos,
                               float* __restrict__ t) {
  int b = blockIdx.x, d = threadIdx.x;
  t[(b * SEQ) * DM + d] = cls[d] + pos[d];
}

// ---------------- generic row-tiled GEMM: C[T x N] = A[T x Kd] @ W + bias ----------------
template <int Kd, int Ncols>
__global__ __launch_bounds__(384) void gemm_rows_kernel(const float* __restrict__ A,
                                                        const float* __restrict__ W,
                                                        const float* __restrict__ bias,
                                                        float* __restrict__ C) {
  __shared__ float xs[8][Kd];
  int r0 = blockIdx.x * 8;           // TOK = 197*8 exactly
  int tid = threadIdx.x;             // 384 threads, Kd==384
#pragma unroll
  for (int r = 0; r < 8; r++) xs[r][tid] = A[(r0 + r) * Kd + tid];
  __syncthreads();
  for (int c = tid; c < Ncols; c += 384) {
    float acc[8];
#pragma unroll
    for (int r = 0; r < 8; r++) acc[r] = 0.f;
    for (int k = 0; k < Kd; k++) {
      float w = W[k * Ncols + c];
#pragma unroll
      for (int r = 0; r < 8; r++) acc[r] += xs[r][k] * w;
    }
    float bb = bias[c];
#pragma unroll
    for (int r = 0; r < 8; r++) C[(r0 + r) * Ncols + c] = acc[r] + bb;
  }
}

// ---------------- attention: one wave per (b, h, q) ----------------
__global__ __launch_bounds__(64) void attn_kernel(const float* __restrict__ qkv,
                                                  float* __restrict__ out) {
  int bi = blockIdx.x;
  int q = bi % SEQ;
  int bh = bi / SEQ;
  int h = bh % NHEAD, b = bh / NHEAD;
  int lane = threadIdx.x;
  __shared__ float qv[HDIM];
  __shared__ float p[SEQ];
  qv[lane] = qkv[(b * SEQ + q) * 1152 + h * HDIM + lane];
  __syncthreads();
  for (int kt = lane; kt < SEQ; kt += 64) {
    const float* krow = qkv + (b * SEQ + kt) * 1152 + DM + h * HDIM;
    float acc = 0.f;
    for (int d2 = 0; d2 < HDIM; d2++) acc += qv[d2] * krow[d2];
    p[kt] = acc * 0.125f;  // 1/sqrt(64)
  }
  __syncthreads();
  float m = -1e30f;
  for (int kt = lane; kt < SEQ; kt += 64) m = fmaxf(m, p[kt]);
  for (int off = 32; off > 0; off >>= 1) m = fmaxf(m, __shfl_xor(m, off));
  float s = 0.f;
  for (int kt = lane; kt < SEQ; kt += 64) { float e2 = __expf(p[kt] - m) ; p[kt] = e2; s += e2; }
  for (int off = 32; off > 0; off >>= 1) s += __shfl_xor(s, off);
  float inv = 1.f / s;
  __syncthreads();
  float acc = 0.f;
  for (int kt = 0; kt < SEQ; kt++)
    acc += p[kt] * qkv[(b * SEQ + kt) * 1152 + 2 * DM + h * HDIM + lane];
  out[(b * SEQ + q) * DM + h * HDIM + lane] = acc * inv;
}

// ---------------- residual add + LayerNorm (per token) ----------------
__global__ __launch_bounds__(384) void add_ln_kernel(float* __restrict__ t,
                                                     const float* __restrict__ delta,
                                                     const float* __restrict__ g,
                                                     const float* __restrict__ bta) {
  int tok = blockIdx.x, d = threadIdx.x;
  float v = t[tok * DM + d] + delta[tok * DM + d];
  float sv = v, sq = v * v;
  for (int off = 32; off > 0; off >>= 1) { sv += __shfl_xor(sv, off); sq += __shfl_xor(sq, off); }
  __shared__ float rs[6], rq[6];
  int w = d >> 6, ln = d & 63;
  if (ln == 0) { rs[w] = sv; rq[w] = sq; }
  __syncthreads();
  float mean = 0.f, ms = 0.f;
#pragma unroll
  for (int i = 0; i < 6; i++) { mean += rs[i]; ms += rq[i]; }
  mean *= (1.f / DM); ms *= (1.f / DM);
  float inv = rsqrtf(ms - mean * mean + EPSLN);
  t[tok * DM + d] = (v - mean) * inv * g[d] + bta[d];
}

// ---------------- router: one wave per token ----------------
__global__ __launch_bounds__(64) void router_kernel(const float* __restrict__ t,
                                                    const float* __restrict__ rw,
                                                    const float* __restrict__ rb,
                                                    unsigned k0, unsigned k1,
                                                    float* __restrict__ gates,
                                                    int* __restrict__ idxb,
                                                    int* __restrict__ lists,
                                                    int* __restrict__ counts,
                                                    int* __restrict__ occ) {
  int tok = blockIdx.x, lane = threadIdx.x;
  int e = lane & 7, j = lane >> 3;
  const float* xr = t + tok * DM;
  float acc = 0.f;
  for (int d2 = j * 48; d2 < j * 48 + 48; d2++) acc += xr[d2] * rw[d2 * NEXP + e];
  acc += __shfl_xor(acc, 8);
  acc += __shfl_xor(acc, 16);
  acc += __shfl_xor(acc, 32);
  if (lane < 8) {
    acc += rb[e];
    // JAX threefry_partitionable=True (default in modern JAX) random_bits for
    // 32-bit output: per flat element i, counter = (uint32(i>>32), uint32(i)),
    // bits = y0 ^ y1.
    unsigned i = (unsigned)(tok * NEXP + e);
    unsigned y0, y1;
    tf2x32(k0, k1, 0u, i, y0, y1);
    unsigned bits = y0 ^ y1;
    float f = __uint_as_float(0x3f800000u | (bits >> 9)) - 1.0f;
    const float lo = -0.99999994f;       // nextafter(-1, 0)
    float u = f * 2.0f + lo;             // (hi-lo) rounds to exactly 2.0f
    u = fmaxf(lo, u);
    acc += 0.01f * (1.41421356f * erfinv32(u));
  }
  float lg[8];
#pragma unroll
  for (int qq = 0; qq < 8; qq++) lg[qq] = __shfl(acc, qq);
  if (lane == 0) {
    int i0 = 0; float v0 = lg[0];
#pragma unroll
    for (int qq = 1; qq < 8; qq++) if (lg[qq] > v0) { v0 = lg[qq]; i0 = qq; }
    int i1 = -1; float v1 = -1e30f;
#pragma unroll
    for (int qq = 0; qq < 8; qq++) if (qq != i0 && lg[qq] > v1) { v1 = lg[qq]; i1 = qq; }
    float e1 = __expf(v1 - v0);
    float g0 = 1.f / (1.f + e1);
    float g1 = 1.f - g0;
    idxb[tok * 2] = i0; idxb[tok * 2 + 1] = i1;
    gates[tok * 2] = g0; gates[tok * 2 + 1] = g1;
    int p0 = atomicAdd(&counts[i0], 1);
    lists[i0 * CAPE + p0] = tok * 2;
    int p1 = atomicAdd(&counts[i1], 1);
    lists[i1 * CAPE + p1] = tok * 2 + 1;
    occ[0 * NEXP + i0] = 1;
    occ[1 * NEXP + i1] = 1;
  }
}

__global__ void zero_kernel(int* __restrict__ counts, int* __restrict__ occ) {
  int i = threadIdx.x;
  if (i < NEXP) counts[i] = 0;
  if (i < 2 * NEXP) occ[i] = 0;
}

// ---------------- bias0[e] = gelu(b1[e]) @ W2[e] + b2[e] ----------------
__global__ __launch_bounds__(384) void bias0_kernel(const float* __restrict__ b1,
                                                    const float* __restrict__ w2,
                                                    const float* __restrict__ b2,
                                                    float* __restrict__ bias0) {
  int e = blockIdx.x, c = threadIdx.x;
  __shared__ float gb[HIDN];
  for (int i = c; i < HIDN; i += 384) gb[i] = gelu_f(b1[e * HIDN + i]);
  __syncthreads();
  float acc = b2[e * DM + c];
  for (int k = 0; k < HIDN; k++) acc += gb[k] * w2[(e * HIDN + k) * DM + c];
  bias0[e * DM + c] = acc;
}

__global__ __launch_bounds__(384) void bias_sum_kernel(const float* __restrict__ bias0,
                                                       const int* __restrict__ occ,
                                                       float* __restrict__ bias_sum) {
  int k = blockIdx.x, d = threadIdx.x;
  float acc = 0.f;
#pragma unroll
  for (int e = 0; e < NEXP; e++)
    if (occ[k * NEXP + e]) acc += bias0[e * DM + d];
  bias_sum[k * DM + d] = acc;
}

// ---------------- fused expert FFN over 16-token tiles ----------------
__global__ __launch_bounds__(384) void moe_kernel(const float* __restrict__ t,
                                                  const float* __restrict__ w1,
                                                  const float* __restrict__ b1,
                                                  const float* __restrict__ w2,
                                                  const float* __restrict__ b2,
                                                  const int* __restrict__ lists,
                                                  const int* __restrict__ counts,
                                                  float* __restrict__ ybuf) {
  int e = blockIdx.y;
  int tile = blockIdx.x;
  int n = counts[e];
  if (tile * 16 >= n) return;
  int rows = min(16, n - tile * 16);
  __shared__ float xs[16][DM];
  __shared__ float hs[16][384];
  __shared__ int ent[16];
  int tid = threadIdx.x;
  if (tid < 16) ent[tid] = (tid < rows) ? lists[e * CAPE + tile * 16 + tid] : 0;
  __syncthreads();
#pragma unroll
  for (int r = 0; r < 16; r++)
    xs[r][tid] = (r < rows) ? t[(ent[r] >> 1) * DM + tid] : 0.f;
  __syncthreads();
  const float* W1 = w1 + e * DM * HIDN;
  const float* W2 = w2 + e * HIDN * DM;
  float acc[16];
#pragma unroll
  for (int r = 0; r < 16; r++) acc[r] = 0.f;
  for (int cc = 0; cc < HIDN / 384; cc++) {
    int hc = cc * 384 + tid;
    float a[16];
    float bb = b1[e * HIDN + hc];
#pragma unroll
    for (int r = 0; r < 16; r++) a[r] = bb;
    for (int k = 0; k < DM; k++) {
      float w = W1[k * HIDN + hc];
#pragma unroll
      for (int r = 0; r < 16; r++) a[r] += xs[r][k] * w;
    }
    __syncthreads();  // protect hs from previous chunk's readers
#pragma unroll
    for (int r = 0; r < 16; r++) hs[r][tid] = gelu_f(a[r]);
    __syncthreads();
    for (int k = 0; k < 384; k++) {
      float w = W2[(cc * 384 + k) * DM + tid];
#pragma unroll
      for (int r = 0; r < 16; r++) acc[r] += hs[r][k] * w;
    }
  }
  float bb2 = b2[e * DM + tid];
  for (int r = 0; r < rows; r++)
    ybuf[ent[r] * DM + tid] = acc[r] + bb2;
}

// ---------------- combine experts + residual + LN2 ----------------
__global__ __launch_bounds__(384) void moe_combine_ln_kernel(float* __restrict__ t,
                                                             const float* __restrict__ ybuf,
                                                             const float* __restrict__ gates,
                                                             const int* __restrict__ idxb,
                                                             const float* __restrict__ bias0,
                                                             const float* __restrict__ bias_sum,
                                                             const float* __restrict__ g,
                                                             const float* __restrict__ bta) {
  int tok = blockIdx.x, d = threadIdx.x;
  float g0 = gates[tok * 2], g1 = gates[tok * 2 + 1];
  int i0 = idxb[tok * 2], i1 = idxb[tok * 2 + 1];
  float m0 = ybuf[(tok * 2) * DM + d] - bias0[i0 * DM + d] + bias_sum[d];
  float m1 = ybuf[(tok * 2 + 1) * DM + d] - bias0[i1 * DM + d] + bias_sum[DM + d];
  float v = t[tok * DM + d] + g0 * m0 + g1 * m1;
  float sv = v, sq = v * v;
  for (int off = 32; off > 0; off >>= 1) { sv += __shfl_xor(sv, off); sq += __shfl_xor(sq, off); }
  __shared__ float rs[6], rq[6];
  int w = d >> 6, ln = d & 63;
  if (ln == 0) { rs[w] = sv; rq[w] = sq; }
  __syncthreads();
  float mean = 0.f, ms = 0.f;
#pragma unroll
  for (int i = 0; i < 6; i++) { mean += rs[i]; ms += rq[i]; }
  mean *= (1.f / DM); ms *= (1.f / DM);
  float inv = rsqrtf(ms - mean * mean + EPSLN);
  t[tok * DM + d] = (v - mean) * inv * g[d] + bta[d];
}

// ---------------- final: LN(cls) @ fc_w + fc_b ----------------
__global__ __launch_bounds__(256) void final_kernel(const float* __restrict__ t,
                                                    const float* __restrict__ ng,
                                                    const float* __restrict__ nb,
                                                    const float* __restrict__ fw,
                                                    const float* __restrict__ fb,
                                                    float* __restrict__ out) {
  int b = blockIdx.x, tid = threadIdx.x;
  __shared__ float xr[DM];
  __shared__ float rs[4], rq[4];
  const float* row = t + (b * SEQ) * DM;
  float sv = 0.f, sq = 0.f;
  for (int i = tid; i < DM; i += 256) { float x = row[i]; xr[i] = x; sv += x; sq += x * x; }
  for (int off = 32; off > 0; off >>= 1) { sv += __shfl_xor(sv, off); sq += __shfl_xor(sq, off); }
  int w = tid >> 6, ln = tid & 63;
  if (ln == 0) { rs[w] = sv; rq[w] = sq; }
  __syncthreads();
  float mean = (rs[0] + rs[1] + rs[2] + rs[3]) * (1.f / DM);
  float ms = (rq[0] + rq[1] + rq[2] + rq[3]) * (1.f / DM);
  float inv = rsqrtf(ms - mean * mean + EPSLN);
  for (int i = tid; i < DM; i += 256) xr[i] = (xr[i] - mean) * inv * ng[i] + nb[i];
  __syncthreads();
  for (int c = tid; c < NCLS; c += 256) {
    float acc = fb[c];
    for (int k = 0; k < DM; k++) acc += xr[k] * fw[k * NCLS + c];
    out[b * NCLS + c] = acc;
  }
}

extern "C" void kernel_launch(void* const* d_in, const int* in_sizes, int n_in,
                              void* d_out, int out_size, void* d_ws, size_t ws_size,
                              hipStream_t stream) {
  const float* x       = (const float*)d_in[0];
  const float* patch_w = (const float*)d_in[1];
  const float* patch_b = (const float*)d_in[2];
  const float* cls_tok = (const float*)d_in[3];
  const float* pos     = (const float*)d_in[4];
  const float* qkv_w   = (const float*)d_in[5];
  const float* qkv_b   = (const float*)d_in[6];
  const float* proj_w  = (const float*)d_in[7];
  const float* proj_b  = (const float*)d_in[8];
  const float* ln1_g   = (const float*)d_in[9];
  const float* ln1_b   = (const float*)d_in[10];
  const float* ln2_g   = (const float*)d_in[11];
  const float* ln2_b   = (const float*)d_in[12];
  const float* router_w = (const float*)d_in[13];
  const float* router_b = (const float*)d_in[14];
  const float* w1      = (const float*)d_in[15];
  const float* b1      = (const float*)d_in[16];
  const float* w2      = (const float*)d_in[17];
  const float* b2      = (const float*)d_in[18];
  const float* norm_g  = (const float*)d_in[19];
  const float* norm_b  = (const float*)d_in[20];
  const float* fc_w    = (const float*)d_in[21];
  const float* fc_b    = (const float*)d_in[22];

  float* ws = (float*)d_ws;
  float* t        = ws;                      // TOK*DM
  float* qkv      = t + TOK * DM;            // TOK*1152
  float* attn     = qkv + TOK * 1152;        // TOK*DM
  float* proj     = attn + TOK * DM;         // TOK*DM
  float* ybuf     = proj + TOK * DM;         // TOK*2*DM
  float* bias0    = ybuf + TOK * 2 * DM;     // NEXP*DM
  float* bias_sum = bias0 + NEXP * DM;       // 2*DM
  float* gates    = bias_sum + 2 * DM;       // TOK*2
  int* idxb   = (int*)(gates + TOK * 2);     // TOK*2
  int* lists  = idxb + TOK * 2;              // NEXP*CAPE
  int* counts = lists + NEXP * CAPE;         // NEXP
  int* occ    = counts + NEXP;               // 2*NEXP

  patch_embed_kernel<<<BATCH * 25, 384, 0, stream>>>(x, patch_w, patch_b, pos, t);
  cls_pos_kernel<<<BATCH, DM, 0, stream>>>(cls_tok, pos, t);

  for (int l = 0; l < LYR; l++) {
    gemm_rows_kernel<DM, 1152><<<TOK / 8, 384, 0, stream>>>(
        t, qkv_w + l * DM * 1152, qkv_b + l * 1152, qkv);
    attn_kernel<<<BATCH * NHEAD * SEQ, 64, 0, stream>>>(qkv, attn);
    gemm_rows_kernel<DM, DM><<<TOK / 8, 384, 0, stream>>>(
        attn, proj_w + l * DM * DM, proj_b + l * DM, proj);
    add_ln_kernel<<<TOK, DM, 0, stream>>>(t, proj, ln1_g + l * DM, ln1_b + l * DM);

    zero_kernel<<<1, 64, 0, stream>>>(counts, occ);
    bias0_kernel<<<NEXP, 384, 0, stream>>>(b1 + l * NEXP * HIDN,
                                           w2 + l * NEXP * HIDN * DM,
                                           b2 + l * NEXP * DM, bias0);
    // fold_in(key(42), l): threefry2x32 with key (0,42), counts (0,l)
    unsigned kl0, kl1;
    tf2x32(0u, 42u, 0u, (unsigned)l, kl0, kl1);
    router_kernel<<<TOK, 64, 0, stream>>>(t, router_w + l * DM * NEXP, router_b + l * NEXP,
                                          kl0, kl1, gates, idxb, lists, counts, occ);
    bias_sum_kernel<<<2, 384, 0, stream>>>(bias0, occ, bias_sum);
    moe_kernel<<<dim3(99, NEXP), 384, 0, stream>>>(t,
                                                   w1 + l * NEXP * DM * HIDN,
                                                   b1 + l * NEXP * HIDN,
                                                   w2 + l * NEXP * HIDN * DM,
                                                   b2 + l * NEXP * DM,
                                                   lists, counts, ybuf);
    moe_combine_ln_kernel<<<TOK, 384, 0, stream>>>(t, ybuf, gates, idxb, bias0, bias_sum,
                                                   ln2_g + l * DM, ln2_b + l * DM);
  }

  final_kernel<<<BATCH, 256, 0, stream>>>(t, norm_g, norm_b, fc_w, fc_b, (float*)d_out);
}

// Round 3
// 2308.017 us; speedup vs baseline: 1.9569x; 1.9569x over previous
//
#include <hip/hip_runtime.h>
#include <hip/hip_bf16.h>

constexpr int LYR  = 4;
constexpr int DM   = 384;
constexpr int HIDN = 1536;
constexpr int NHEAD = 6;
constexpr int HDIM = 64;
constexpr int NEXP = 8;
constexpr int SEQ  = 197;
constexpr int BATCH = 8;
constexpr int TOK  = BATCH * SEQ;   // 1576
constexpr int NCLS = 1000;
constexpr int CAPE = TOK;           // max pairs per expert
constexpr int NPATCH = BATCH * 196; // 1568
constexpr float EPSLN = 1e-5f;

// ---------------- threefry2x32 (JAX-compatible) ----------------
__host__ __device__ inline void tf2x32(unsigned k0, unsigned k1, unsigned x0, unsigned x1,
                                       unsigned& y0, unsigned& y1) {
  unsigned ks2 = k0 ^ k1 ^ 0x1BD11BDAu;
  unsigned v0 = x0 + k0, v1 = x1 + k1;
#define TFR(r) { v0 += v1; v1 = (v1 << (r)) | (v1 >> (32 - (r))); v1 ^= v0; }
  TFR(13) TFR(15) TFR(26) TFR(6)
  v0 += k1;  v1 += ks2 + 1u;
  TFR(17) TFR(29) TFR(16) TFR(24)
  v0 += ks2; v1 += k0 + 2u;
  TFR(13) TFR(15) TFR(26) TFR(6)
  v0 += k0;  v1 += k1 + 3u;
  TFR(17) TFR(29) TFR(16) TFR(24)
  v0 += k1;  v1 += ks2 + 4u;
  TFR(13) TFR(15) TFR(26) TFR(6)
  v0 += ks2; v1 += k0 + 5u;
#undef TFR
  y0 = v0; y1 = v1;
}

// XLA ErfInv32 (Giles) — matches jax.lax.erf_inv for f32
__device__ inline float erfinv32(float x) {
  float w = -log1pf(-x * x);
  float p;
  if (w < 5.f) {
    w -= 2.5f;
    p = 2.81022636e-08f;
    p = fmaf(p, w, 3.43273939e-07f);
    p = fmaf(p, w, -3.5233877e-06f);
    p = fmaf(p, w, -4.39150654e-06f);
    p = fmaf(p, w, 0.00021858087f);
    p = fmaf(p, w, -0.00125372503f);
    p = fmaf(p, w, -0.00417768164f);
    p = fmaf(p, w, 0.246640727f);
    p = fmaf(p, w, 1.50140941f);
  } else {
    w = sqrtf(w) - 3.f;
    p = -0.000200214257f;
    p = fmaf(p, w, 0.000100950558f);
    p = fmaf(p, w, 0.00134934322f);
    p = fmaf(p, w, -0.00367342844f);
    p = fmaf(p, w, 0.00573950773f);
    p = fmaf(p, w, -0.0076224613f);
    p = fmaf(p, w, 0.00943887047f);
    p = fmaf(p, w, 1.00167406f);
    p = fmaf(p, w, 2.83297682f);
  }
  return p * x;
}

__device__ inline float gelu_f(float x) {
  return 0.5f * x * (1.f + erff(x * 0.70710678118654752f));
}

// =====================================================================
// Tiled fp32 GEMM core: 64x64 tile, 256 threads, 4x4 per thread, BK=16.
// xs stored transposed [k][row] so compute reads are float4; wsh [k][col].
// =====================================================================
#define GEMM_FMA_BODY()                                                     \
  _Pragma("unroll")                                                         \
  for (int k = 0; k < 16; k++) {                                            \
    const float4 a4 = *(const float4*)&xs[k][ty << 2];                      \
    const float4 b4 = *(const float4*)&wsh[k][tx << 2];                     \
    const float aa[4] = {a4.x, a4.y, a4.z, a4.w};                           \
    const float bb[4] = {b4.x, b4.y, b4.z, b4.w};                           \
    _Pragma("unroll")                                                       \
    for (int i = 0; i < 4; i++)                                             \
      _Pragma("unroll")                                                     \
      for (int j = 0; j < 4; j++) acc[i][j] = fmaf(aa[i], bb[j], acc[i][j]);\
  }

// C[M x N] = A[M x K] @ W + bias, row-major everywhere.
template <int KTOT, int NTOT>
__global__ __launch_bounds__(256) void gemm64_kernel(const float* __restrict__ A,
                                                     const float* __restrict__ W,
                                                     const float* __restrict__ bias,
                                                     float* __restrict__ C, int M) {
  __shared__ float xs[16][68];
  __shared__ float wsh[16][68];
  const int r0 = blockIdx.x * 64, c0 = blockIdx.y * 64;
  const int rows = min(64, M - r0);
  const int tid = threadIdx.x;
  const int tx = tid & 15, ty = tid >> 4;
  const int sr = tid >> 2, skq = (tid & 3) << 2;   // A-stage: row, k-quad
  const int wk = tid >> 4, wc = (tid & 15) << 2;   // W-stage: k, col-quad
  float acc[4][4] = {};
  for (int k0 = 0; k0 < KTOT; k0 += 16) {
    float4 av = make_float4(0.f, 0.f, 0.f, 0.f);
    if (sr < rows) av = *(const float4*)&A[(r0 + sr) * KTOT + k0 + skq];
    const float4 wv = *(const float4*)&W[(k0 + wk) * NTOT + c0 + wc];
    __syncthreads();
    xs[skq + 0][sr] = av.x; xs[skq + 1][sr] = av.y;
    xs[skq + 2][sr] = av.z; xs[skq + 3][sr] = av.w;
    *(float4*)&wsh[wk][wc] = wv;
    __syncthreads();
    GEMM_FMA_BODY()
  }
  const float4 bv = *(const float4*)&bias[c0 + (tx << 2)];
#pragma unroll
  for (int i = 0; i < 4; i++) {
    const int r = (ty << 2) + i;
    if (r < rows) {
      float4 o = make_float4(acc[i][0] + bv.x, acc[i][1] + bv.y,
                             acc[i][2] + bv.z, acc[i][3] + bv.w);
      *(float4*)&C[(r0 + r) * NTOT + c0 + (tx << 2)] = o;
    }
  }
}

// Patch embed as GEMM: A gathered from image (unfold), +patch_b +pos, into t.
__global__ __launch_bounds__(256) void patch_gemm_kernel(const float* __restrict__ x,
                                                         const float* __restrict__ pw,
                                                         const float* __restrict__ pb,
                                                         const float* __restrict__ pos,
                                                         float* __restrict__ t) {
  __shared__ float xs[16][68];
  __shared__ float wsh[16][68];
  const int r0 = blockIdx.x * 64, c0 = blockIdx.y * 64;
  const int rows = min(64, NPATCH - r0);
  const int tid = threadIdx.x;
  const int tx = tid & 15, ty = tid >> 4;
  const int sr = tid >> 2, skq = (tid & 3) << 2;
  const int wk = tid >> 4, wc = (tid & 15) << 2;
  const int p = r0 + sr;
  const bool okr = (sr < rows);
  const int b = p / 196, n = p - b * 196;
  const int hp = n / 14, wp = n - hp * 14;
  const float* xbase = x + ((long)(b * 3) * 224 + hp * 16) * 224 + wp * 16;
  float acc[4][4] = {};
  for (int k0 = 0; k0 < 768; k0 += 16) {
    const int f = k0 + skq;
    const int c = f >> 8, py = (f >> 4) & 15, px = f & 15;
    float4 av = make_float4(0.f, 0.f, 0.f, 0.f);
    if (okr) av = *(const float4*)&xbase[((long)c * 224 + py) * 224 + px];
    const float4 wv = *(const float4*)&pw[(k0 + wk) * DM + c0 + wc];
    __syncthreads();
    xs[skq + 0][sr] = av.x; xs[skq + 1][sr] = av.y;
    xs[skq + 2][sr] = av.z; xs[skq + 3][sr] = av.w;
    *(float4*)&wsh[wk][wc] = wv;
    __syncthreads();
    GEMM_FMA_BODY()
  }
  const float4 bv = *(const float4*)&pb[c0 + (tx << 2)];
#pragma unroll
  for (int i = 0; i < 4; i++) {
    const int r = (ty << 2) + i;
    if (r < rows) {
      const int p2 = r0 + r;
      const int b2_ = p2 / 196, n2 = p2 - b2_ * 196;
      const float4 pv = *(const float4*)&pos[(1 + n2) * DM + c0 + (tx << 2)];
      float4 o = make_float4(acc[i][0] + bv.x + pv.x, acc[i][1] + bv.y + pv.y,
                             acc[i][2] + bv.z + pv.z, acc[i][3] + bv.w + pv.w);
      *(float4*)&t[(b2_ * SEQ + 1 + n2) * DM + c0 + (tx << 2)] = o;
    }
  }
}

// MoE phase 1: h[pid] = gelu(t[tok] @ W1_e + b1_e), rows gathered by expert list.
__global__ __launch_bounds__(256) void moe1_kernel(const float* __restrict__ t,
                                                   const float* __restrict__ w1,
                                                   const float* __restrict__ b1,
                                                   const int* __restrict__ lists,
                                                   const int* __restrict__ counts,
                                                   float* __restrict__ h) {
  const int e = blockIdx.y;
  const int n = counts[e];
  const int rt = blockIdx.x;
  if (rt * 64 >= n) return;
  const int ct = blockIdx.z;
  const int rows = min(64, n - rt * 64);
  __shared__ int ent[64];
  __shared__ float xs[16][68];
  __shared__ float wsh[16][68];
  const int tid = threadIdx.x;
  if (tid < 64) ent[tid] = (tid < rows) ? lists[e * CAPE + rt * 64 + tid] : -1;
  const int tx = tid & 15, ty = tid >> 4;
  const int sr = tid >> 2, skq = (tid & 3) << 2;
  const int wk = tid >> 4, wc = (tid & 15) << 2;
  const float* W = w1 + (long)e * DM * HIDN;
  const int c0 = ct * 64;
  __syncthreads();
  const int myrow = ent[sr] >> 1;  // token index; -1 stays -1
  float acc[4][4] = {};
  for (int k0 = 0; k0 < DM; k0 += 16) {
    float4 av = make_float4(0.f, 0.f, 0.f, 0.f);
    if (myrow >= 0) av = *(const float4*)&t[myrow * DM + k0 + skq];
    const float4 wv = *(const float4*)&W[(long)(k0 + wk) * HIDN + c0 + wc];
    __syncthreads();
    xs[skq + 0][sr] = av.x; xs[skq + 1][sr] = av.y;
    xs[skq + 2][sr] = av.z; xs[skq + 3][sr] = av.w;
    *(float4*)&wsh[wk][wc] = wv;
    __syncthreads();
    GEMM_FMA_BODY()
  }
  const float4 bv = *(const float4*)&b1[e * HIDN + c0 + (tx << 2)];
#pragma unroll
  for (int i = 0; i < 4; i++) {
    const int r = (ty << 2) + i;
    if (r < rows) {
      const int pid = ent[r];
      float* hp2 = &h[(long)pid * HIDN + c0 + (tx << 2)];
      hp2[0] = gelu_f(acc[i][0] + bv.x);
      hp2[1] = gelu_f(acc[i][1] + bv.y);
      hp2[2] = gelu_f(acc[i][2] + bv.z);
      hp2[3] = gelu_f(acc[i][3] + bv.w);
    }
  }
}

// MoE phase 2: ybuf[pid] = h[pid] @ W2_e + b2_e
__global__ __launch_bounds__(256) void moe2_kernel(const float* __restrict__ h,
                                                   const float* __restrict__ w2,
                                                   const float* __restrict__ b2,
                                                   const int* __restrict__ lists,
                                                   const int* __restrict__ counts,
                                                   float* __restrict__ ybuf) {
  const int e = blockIdx.y;
  const int n = counts[e];
  const int rt = blockIdx.x;
  if (rt * 64 >= n) return;
  const int ct = blockIdx.z;
  const int rows = min(64, n - rt * 64);
  __shared__ int ent[64];
  __shared__ float xs[16][68];
  __shared__ float wsh[16][68];
  const int tid = threadIdx.x;
  if (tid < 64) ent[tid] = (tid < rows) ? lists[e * CAPE + rt * 64 + tid] : -1;
  const int tx = tid & 15, ty = tid >> 4;
  const int sr = tid >> 2, skq = (tid & 3) << 2;
  const int wk = tid >> 4, wc = (tid & 15) << 2;
  const float* W = w2 + (long)e * HIDN * DM;
  const int c0 = ct * 64;
  __syncthreads();
  const int mypid = ent[sr];
  float acc[4][4] = {};
  for (int k0 = 0; k0 < HIDN; k0 += 16) {
    float4 av = make_float4(0.f, 0.f, 0.f, 0.f);
    if (mypid >= 0) av = *(const float4*)&h[(long)mypid * HIDN + k0 + skq];
    const float4 wv = *(const float4*)&W[(long)(k0 + wk) * DM + c0 + wc];
    __syncthreads();
    xs[skq + 0][sr] = av.x; xs[skq + 1][sr] = av.y;
    xs[skq + 2][sr] = av.z; xs[skq + 3][sr] = av.w;
    *(float4*)&wsh[wk][wc] = wv;
    __syncthreads();
    GEMM_FMA_BODY()
  }
  const float4 bv = *(const float4*)&b2[e * DM + c0 + (tx << 2)];
#pragma unroll
  for (int i = 0; i < 4; i++) {
    const int r = (ty << 2) + i;
    if (r < rows) {
      const int pid = ent[r];
      float4 o = make_float4(acc[i][0] + bv.x, acc[i][1] + bv.y,
                             acc[i][2] + bv.z, acc[i][3] + bv.w);
      *(float4*)&ybuf[(long)pid * DM + c0 + (tx << 2)] = o;
    }
  }
}

__global__ void cls_pos_kernel(const float* __restrict__ cls, const float* __restrict__ pos,
                               float* __restrict__ t) {
  int b = blockIdx.x, d = threadIdx.x;
  t[(b * SEQ) * DM + d] = cls[d] + pos[d];
}

// ---------------- attention: one wave per (b, h, q) ----------------
__global__ __launch_bounds__(64) void attn_kernel(const float* __restrict__ qkv,
                                                  float* __restrict__ out) {
  int bi = blockIdx.x;
  int q = bi % SEQ;
  int bh = bi / SEQ;
  int h = bh % NHEAD, b = bh / NHEAD;
  int lane = threadIdx.x;
  __shared__ float qv[HDIM];
  __shared__ float p[SEQ];
  qv[lane] = qkv[(b * SEQ + q) * 1152 + h * HDIM + lane];
  __syncthreads();
  for (int kt = lane; kt < SEQ; kt += 64) {
    const float* krow = qkv + (b * SEQ + kt) * 1152 + DM + h * HDIM;
    float acc = 0.f;
    for (int d2 = 0; d2 < HDIM; d2++) acc += qv[d2] * krow[d2];
    p[kt] = acc * 0.125f;
  }
  __syncthreads();
  float m = -1e30f;
  for (int kt = lane; kt < SEQ; kt += 64) m = fmaxf(m, p[kt]);
  for (int off = 32; off > 0; off >>= 1) m = fmaxf(m, __shfl_xor(m, off));
  float s = 0.f;
  for (int kt = lane; kt < SEQ; kt += 64) { float e2 = __expf(p[kt] - m); p[kt] = e2; s += e2; }
  for (int off = 32; off > 0; off >>= 1) s += __shfl_xor(s, off);
  float inv = 1.f / s;
  __syncthreads();
  float acc = 0.f;
  for (int kt = 0; kt < SEQ; kt++)
    acc += p[kt] * qkv[(b * SEQ + kt) * 1152 + 2 * DM + h * HDIM + lane];
  out[(b * SEQ + q) * DM + h * HDIM + lane] = acc * inv;
}

// ---------------- residual add + LayerNorm (per token) ----------------
__global__ __launch_bounds__(384) void add_ln_kernel(float* __restrict__ t,
                                                     const float* __restrict__ delta,
                                                     const float* __restrict__ g,
                                                     const float* __restrict__ bta) {
  int tok = blockIdx.x, d = threadIdx.x;
  float v = t[tok * DM + d] + delta[tok * DM + d];
  float sv = v, sq = v * v;
  for (int off = 32; off > 0; off >>= 1) { sv += __shfl_xor(sv, off); sq += __shfl_xor(sq, off); }
  __shared__ float rs[6], rq[6];
  int w = d >> 6, ln = d & 63;
  if (ln == 0) { rs[w] = sv; rq[w] = sq; }
  __syncthreads();
  float mean = 0.f, ms = 0.f;
#pragma unroll
  for (int i = 0; i < 6; i++) { mean += rs[i]; ms += rq[i]; }
  mean *= (1.f / DM); ms *= (1.f / DM);
  float inv = rsqrtf(ms - mean * mean + EPSLN);
  t[tok * DM + d] = (v - mean) * inv * g[d] + bta[d];
}

// ---------------- router: one wave per token ----------------
__global__ __launch_bounds__(64) void router_kernel(const float* __restrict__ t,
                                                    const float* __restrict__ rw,
                                                    const float* __restrict__ rb,
                                                    unsigned k0, unsigned k1,
                                                    float* __restrict__ gates,
                                                    int* __restrict__ idxb,
                                                    int* __restrict__ lists,
                                                    int* __restrict__ counts,
                                                    int* __restrict__ occ) {
  int tok = blockIdx.x, lane = threadIdx.x;
  int e = lane & 7, j = lane >> 3;
  const float* xr = t + tok * DM;
  float acc = 0.f;
  for (int d2 = j * 48; d2 < j * 48 + 48; d2++) acc += xr[d2] * rw[d2 * NEXP + e];
  acc += __shfl_xor(acc, 8);
  acc += __shfl_xor(acc, 16);
  acc += __shfl_xor(acc, 32);
  if (lane < 8) {
    acc += rb[e];
    // JAX threefry_partitionable random_bits: counter=(0,i), bits = y0^y1
    unsigned i = (unsigned)(tok * NEXP + e);
    unsigned y0, y1;
    tf2x32(k0, k1, 0u, i, y0, y1);
    unsigned bits = y0 ^ y1;
    float f = __uint_as_float(0x3f800000u | (bits >> 9)) - 1.0f;
    const float lo = -0.99999994f;
    float u = f * 2.0f + lo;
    u = fmaxf(lo, u);
    acc += 0.01f * (1.41421356f * erfinv32(u));
  }
  float lg[8];
#pragma unroll
  for (int qq = 0; qq < 8; qq++) lg[qq] = __shfl(acc, qq);
  if (lane == 0) {
    int i0 = 0; float v0 = lg[0];
#pragma unroll
    for (int qq = 1; qq < 8; qq++) if (lg[qq] > v0) { v0 = lg[qq]; i0 = qq; }
    int i1 = -1; float v1 = -1e30f;
#pragma unroll
    for (int qq = 0; qq < 8; qq++) if (qq != i0 && lg[qq] > v1) { v1 = lg[qq]; i1 = qq; }
    float e1 = __expf(v1 - v0);
    float g0 = 1.f / (1.f + e1);
    float g1 = 1.f - g0;
    idxb[tok * 2] = i0; idxb[tok * 2 + 1] = i1;
    gates[tok * 2] = g0; gates[tok * 2 + 1] = g1;
    int p0 = atomicAdd(&counts[i0], 1);
    lists[i0 * CAPE + p0] = tok * 2;
    int p1 = atomicAdd(&counts[i1], 1);
    lists[i1 * CAPE + p1] = tok * 2 + 1;
    occ[0 * NEXP + i0] = 1;
    occ[1 * NEXP + i1] = 1;
  }
}

// ---------------- prep: bias0 = b2, zero counts/occ ----------------
__global__ void prep_kernel(const float* __restrict__ b2, float* __restrict__ bias0,
                            int* __restrict__ counts, int* __restrict__ occ) {
  int e = blockIdx.x, c = threadIdx.x;
  bias0[e * DM + c] = b2[e * DM + c];
  if (e == 0) {
    if (c < NEXP) counts[c] = 0;
    if (c < 2 * NEXP) occ[c] = 0;
  }
}

// ---------------- bias0 += gelu(b1)@W2 partial over K-chunks ----------------
__global__ __launch_bounds__(384) void bias0_partial_kernel(const float* __restrict__ b1,
                                                            const float* __restrict__ w2,
                                                            float* __restrict__ bias0) {
  const int e = blockIdx.x, kc = blockIdx.y;
  __shared__ float gb[128];
  const int tid = threadIdx.x;
  if (tid < 128) gb[tid] = gelu_f(b1[e * HIDN + kc * 128 + tid]);
  __syncthreads();
  float acc = 0.f;
  const float* W = w2 + ((long)e * HIDN + kc * 128) * DM + tid;
  for (int j2 = 0; j2 < 128; j2++) acc += gb[j2] * W[(long)j2 * DM];
  atomicAdd(&bias0[e * DM + tid], acc);
}

__global__ __launch_bounds__(384) void bias_sum_kernel(const float* __restrict__ bias0,
                                                       const int* __restrict__ occ,
                                                       float* __restrict__ bias_sum) {
  int k = blockIdx.x, d = threadIdx.x;
  float acc = 0.f;
#pragma unroll
  for (int e = 0; e < NEXP; e++)
    if (occ[k * NEXP + e]) acc += bias0[e * DM + d];
  bias_sum[k * DM + d] = acc;
}

// ---------------- combine experts + residual + LN2 ----------------
__global__ __launch_bounds__(384) void moe_combine_ln_kernel(float* __restrict__ t,
                                                             const float* __restrict__ ybuf,
                                                             const float* __restrict__ gates,
                                                             const int* __restrict__ idxb,
                                                             const float* __restrict__ bias0,
                                                             const float* __restrict__ bias_sum,
                                                             const float* __restrict__ g,
                                                             const float* __restrict__ bta) {
  int tok = blockIdx.x, d = threadIdx.x;
  float g0 = gates[tok * 2], g1 = gates[tok * 2 + 1];
  int i0 = idxb[tok * 2], i1 = idxb[tok * 2 + 1];
  float m0 = ybuf[(tok * 2) * DM + d] - bias0[i0 * DM + d] + bias_sum[d];
  float m1 = ybuf[(tok * 2 + 1) * DM + d] - bias0[i1 * DM + d] + bias_sum[DM + d];
  float v = t[tok * DM + d] + g0 * m0 + g1 * m1;
  float sv = v, sq = v * v;
  for (int off = 32; off > 0; off >>= 1) { sv += __shfl_xor(sv, off); sq += __shfl_xor(sq, off); }
  __shared__ float rs[6], rq[6];
  int w = d >> 6, ln = d & 63;
  if (ln == 0) { rs[w] = sv; rq[w] = sq; }
  __syncthreads();
  float mean = 0.f, ms = 0.f;
#pragma unroll
  for (int i = 0; i < 6; i++) { mean += rs[i]; ms += rq[i]; }
  mean *= (1.f / DM); ms *= (1.f / DM);
  float inv = rsqrtf(ms - mean * mean + EPSLN);
  t[tok * DM + d] = (v - mean) * inv * g[d] + bta[d];
}

// ---------------- final: LN(cls) @ fc_w + fc_b, split over col chunks ----------------
__global__ __launch_bounds__(256) void final_kernel(const float* __restrict__ t,
                                                    const float* __restrict__ ng,
                                                    const float* __restrict__ nb,
                                                    const float* __restrict__ fw,
                                                    const float* __restrict__ fb,
                                                    float* __restrict__ out) {
  int b = blockIdx.x, chunk = blockIdx.y, tid = threadIdx.x;
  __shared__ float xr[DM];
  __shared__ float rs[4], rq[4];
  const float* row = t + (b * SEQ) * DM;
  float sv = 0.f, sq = 0.f;
  for (int i = tid; i < DM; i += 256) { float x = row[i]; xr[i] = x; sv += x; sq += x * x; }
  for (int off = 32; off > 0; off >>= 1) { sv += __shfl_xor(sv, off); sq += __shfl_xor(sq, off); }
  int w = tid >> 6, ln = tid & 63;
  if (ln == 0) { rs[w] = sv; rq[w] = sq; }
  __syncthreads();
  float mean = (rs[0] + rs[1] + rs[2] + rs[3]) * (1.f / DM);
  float ms = (rq[0] + rq[1] + rq[2] + rq[3]) * (1.f / DM);
  float inv = rsqrtf(ms - mean * mean + EPSLN);
  for (int i = tid; i < DM; i += 256) xr[i] = (xr[i] - mean) * inv * ng[i] + nb[i];
  __syncthreads();
  int c = chunk * 250 + tid;
  if (tid < 250) {
    float acc = fb[c];
    for (int k = 0; k < DM; k++) acc += xr[k] * fw[k * NCLS + c];
    out[b * NCLS + c] = acc;
  }
}

extern "C" void kernel_launch(void* const* d_in, const int* in_sizes, int n_in,
                              void* d_out, int out_size, void* d_ws, size_t ws_size,
                              hipStream_t stream) {
  const float* x       = (const float*)d_in[0];
  const float* patch_w = (const float*)d_in[1];
  const float* patch_b = (const float*)d_in[2];
  const float* cls_tok = (const float*)d_in[3];
  const float* pos     = (const float*)d_in[4];
  const float* qkv_w   = (const float*)d_in[5];
  const float* qkv_b   = (const float*)d_in[6];
  const float* proj_w  = (const float*)d_in[7];
  const float* proj_b  = (const float*)d_in[8];
  const float* ln1_g   = (const float*)d_in[9];
  const float* ln1_b   = (const float*)d_in[10];
  const float* ln2_g   = (const float*)d_in[11];
  const float* ln2_b   = (const float*)d_in[12];
  const float* router_w = (const float*)d_in[13];
  const float* router_b = (const float*)d_in[14];
  const float* w1      = (const float*)d_in[15];
  const float* b1      = (const float*)d_in[16];
  const float* w2      = (const float*)d_in[17];
  const float* b2      = (const float*)d_in[18];
  const float* norm_g  = (const float*)d_in[19];
  const float* norm_b  = (const float*)d_in[20];
  const float* fc_w    = (const float*)d_in[21];
  const float* fc_b    = (const float*)d_in[22];

  float* ws = (float*)d_ws;
  float* t        = ws;                      // TOK*DM
  float* qkv      = t + TOK * DM;            // TOK*1152
  float* attn     = qkv + TOK * 1152;        // TOK*DM
  float* proj     = attn + TOK * DM;         // TOK*DM
  float* ybuf     = proj + TOK * DM;         // TOK*2*DM
  float* bias0    = ybuf + TOK * 2 * DM;     // NEXP*DM
  float* bias_sum = bias0 + NEXP * DM;       // 2*DM
  float* gates    = bias_sum + 2 * DM;       // TOK*2
  int* idxb   = (int*)(gates + TOK * 2);     // TOK*2
  int* lists  = idxb + TOK * 2;              // NEXP*CAPE
  int* counts = lists + NEXP * CAPE;         // NEXP
  int* occ    = counts + NEXP;               // 2*NEXP
  float* hbuf = (float*)(occ + 2 * NEXP);    // 2*TOK*HIDN  (~19.4 MB)

  patch_gemm_kernel<<<dim3(25, 6), 256, 0, stream>>>(x, patch_w, patch_b, pos, t);
  cls_pos_kernel<<<BATCH, DM, 0, stream>>>(cls_tok, pos, t);

  for (int l = 0; l < LYR; l++) {
    gemm64_kernel<DM, 1152><<<dim3(25, 18), 256, 0, stream>>>(
        t, qkv_w + (long)l * DM * 1152, qkv_b + l * 1152, qkv, TOK);
    attn_kernel<<<BATCH * NHEAD * SEQ, 64, 0, stream>>>(qkv, attn);
    gemm64_kernel<DM, DM><<<dim3(25, 6), 256, 0, stream>>>(
        attn, proj_w + (long)l * DM * DM, proj_b + l * DM, proj, TOK);
    add_ln_kernel<<<TOK, DM, 0, stream>>>(t, proj, ln1_g + l * DM, ln1_b + l * DM);

    prep_kernel<<<NEXP, DM, 0, stream>>>(b2 + l * NEXP * DM, bias0, counts, occ);
    bias0_partial_kernel<<<dim3(NEXP, 12), 384, 0, stream>>>(
        b1 + l * NEXP * HIDN, w2 + (long)l * NEXP * HIDN * DM, bias0);
    unsigned kl0, kl1;
    tf2x32(0u, 42u, 0u, (unsigned)l, kl0, kl1);
    router_kernel<<<TOK, 64, 0, stream>>>(t, router_w + l * DM * NEXP, router_b + l * NEXP,
                                          kl0, kl1, gates, idxb, lists, counts, occ);
    bias_sum_kernel<<<2, 384, 0, stream>>>(bias0, occ, bias_sum);
    moe1_kernel<<<dim3(25, NEXP, 24), 256, 0, stream>>>(
        t, w1 + (long)l * NEXP * DM * HIDN, b1 + l * NEXP * HIDN, lists, counts, hbuf);
    moe2_kernel<<<dim3(25, NEXP, 6), 256, 0, stream>>>(
        hbuf, w2 + (long)l * NEXP * HIDN * DM, b2 + l * NEXP * DM, lists, counts, ybuf);
    moe_combine_ln_kernel<<<TOK, DM, 0, stream>>>(t, ybuf, gates, idxb, bias0, bias_sum,
                                                  ln2_g + l * DM, ln2_b + l * DM);
  }

  final_kernel<<<dim3(BATCH, 4), 256, 0, stream>>>(t, norm_g, norm_b, fc_w, fc_b,
                                                   (float*)d_out);
}

// Round 4
// 1763.356 us; speedup vs baseline: 2.5613x; 1.3089x over previous
//
#include <hip/hip_runtime.h>
#include <hip/hip_bf16.h>

constexpr int LYR  = 4;
constexpr int DM   = 384;
constexpr int HIDN = 1536;
constexpr int NHEAD = 6;
constexpr int HDIM = 64;
constexpr int NEXP = 8;
constexpr int SEQ  = 197;
constexpr int BATCH = 8;
constexpr int TOK  = BATCH * SEQ;   // 1576
constexpr int NCLS = 1000;
constexpr int CAPE = TOK;           // max pairs per expert
constexpr int NPATCH = BATCH * 196; // 1568
constexpr float EPSLN = 1e-5f;

// ---------------- threefry2x32 (JAX-compatible) ----------------
__host__ __device__ inline void tf2x32(unsigned k0, unsigned k1, unsigned x0, unsigned x1,
                                       unsigned& y0, unsigned& y1) {
  unsigned ks2 = k0 ^ k1 ^ 0x1BD11BDAu;
  unsigned v0 = x0 + k0, v1 = x1 + k1;
#define TFR(r) { v0 += v1; v1 = (v1 << (r)) | (v1 >> (32 - (r))); v1 ^= v0; }
  TFR(13) TFR(15) TFR(26) TFR(6)
  v0 += k1;  v1 += ks2 + 1u;
  TFR(17) TFR(29) TFR(16) TFR(24)
  v0 += ks2; v1 += k0 + 2u;
  TFR(13) TFR(15) TFR(26) TFR(6)
  v0 += k0;  v1 += k1 + 3u;
  TFR(17) TFR(29) TFR(16) TFR(24)
  v0 += k1;  v1 += ks2 + 4u;
  TFR(13) TFR(15) TFR(26) TFR(6)
  v0 += ks2; v1 += k0 + 5u;
#undef TFR
  y0 = v0; y1 = v1;
}

// XLA ErfInv32 (Giles) — matches jax.lax.erf_inv for f32
__device__ inline float erfinv32(float x) {
  float w = -log1pf(-x * x);
  float p;
  if (w < 5.f) {
    w -= 2.5f;
    p = 2.81022636e-08f;
    p = fmaf(p, w, 3.43273939e-07f);
    p = fmaf(p, w, -3.5233877e-06f);
    p = fmaf(p, w, -4.39150654e-06f);
    p = fmaf(p, w, 0.00021858087f);
    p = fmaf(p, w, -0.00125372503f);
    p = fmaf(p, w, -0.00417768164f);
    p = fmaf(p, w, 0.246640727f);
    p = fmaf(p, w, 1.50140941f);
  } else {
    w = sqrtf(w) - 3.f;
    p = -0.000200214257f;
    p = fmaf(p, w, 0.000100950558f);
    p = fmaf(p, w, 0.00134934322f);
    p = fmaf(p, w, -0.00367342844f);
    p = fmaf(p, w, 0.00573950773f);
    p = fmaf(p, w, -0.0076224613f);
    p = fmaf(p, w, 0.00943887047f);
    p = fmaf(p, w, 1.00167406f);
    p = fmaf(p, w, 2.83297682f);
  }
  return p * x;
}

__device__ inline float gelu_f(float x) {
  return 0.5f * x * (1.f + erff(x * 0.70710678118654752f));
}

// =====================================================================
// Tiled fp32 GEMM core: 64x64 tile, 256 threads, 4x4 per thread, BK=16.
// =====================================================================
#define GEMM_FMA_BODY()                                                     \
  _Pragma("unroll")                                                         \
  for (int k = 0; k < 16; k++) {                                            \
    const float4 a4 = *(const float4*)&xs[k][ty << 2];                      \
    const float4 b4 = *(const float4*)&wsh[k][tx << 2];                     \
    const float aa[4] = {a4.x, a4.y, a4.z, a4.w};                           \
    const float bb[4] = {b4.x, b4.y, b4.z, b4.w};                           \
    _Pragma("unroll")                                                       \
    for (int i = 0; i < 4; i++)                                             \
      _Pragma("unroll")                                                     \
      for (int j = 0; j < 4; j++) acc[i][j] = fmaf(aa[i], bb[j], acc[i][j]);\
  }

template <int KTOT, int NTOT>
__global__ __launch_bounds__(256) void gemm64_kernel(const float* __restrict__ A,
                                                     const float* __restrict__ W,
                                                     const float* __restrict__ bias,
                                                     float* __restrict__ C, int M) {
  __shared__ float xs[16][68];
  __shared__ float wsh[16][68];
  const int r0 = blockIdx.x * 64, c0 = blockIdx.y * 64;
  const int rows = min(64, M - r0);
  const int tid = threadIdx.x;
  const int tx = tid & 15, ty = tid >> 4;
  const int sr = tid >> 2, skq = (tid & 3) << 2;
  const int wk = tid >> 4, wc = (tid & 15) << 2;
  float acc[4][4] = {};
  for (int k0 = 0; k0 < KTOT; k0 += 16) {
    float4 av = make_float4(0.f, 0.f, 0.f, 0.f);
    if (sr < rows) av = *(const float4*)&A[(r0 + sr) * KTOT + k0 + skq];
    const float4 wv = *(const float4*)&W[(k0 + wk) * NTOT + c0 + wc];
    __syncthreads();
    xs[skq + 0][sr] = av.x; xs[skq + 1][sr] = av.y;
    xs[skq + 2][sr] = av.z; xs[skq + 3][sr] = av.w;
    *(float4*)&wsh[wk][wc] = wv;
    __syncthreads();
    GEMM_FMA_BODY()
  }
  const float4 bv = *(const float4*)&bias[c0 + (tx << 2)];
#pragma unroll
  for (int i = 0; i < 4; i++) {
    const int r = (ty << 2) + i;
    if (r < rows) {
      float4 o = make_float4(acc[i][0] + bv.x, acc[i][1] + bv.y,
                             acc[i][2] + bv.z, acc[i][3] + bv.w);
      *(float4*)&C[(r0 + r) * NTOT + c0 + (tx << 2)] = o;
    }
  }
}

// Patch embed as GEMM: A gathered from image (unfold), +patch_b +pos, into t.
__global__ __launch_bounds__(256) void patch_gemm_kernel(const float* __restrict__ x,
                                                         const float* __restrict__ pw,
                                                         const float* __restrict__ pb,
                                                         const float* __restrict__ pos,
                                                         float* __restrict__ t) {
  __shared__ float xs[16][68];
  __shared__ float wsh[16][68];
  const int r0 = blockIdx.x * 64, c0 = blockIdx.y * 64;
  const int rows = min(64, NPATCH - r0);
  const int tid = threadIdx.x;
  const int tx = tid & 15, ty = tid >> 4;
  const int sr = tid >> 2, skq = (tid & 3) << 2;
  const int wk = tid >> 4, wc = (tid & 15) << 2;
  const int p = r0 + sr;
  const bool okr = (sr < rows);
  const int b = p / 196, n = p - b * 196;
  const int hp = n / 14, wp = n - hp * 14;
  const float* xbase = x + ((long)(b * 3) * 224 + hp * 16) * 224 + wp * 16;
  float acc[4][4] = {};
  for (int k0 = 0; k0 < 768; k0 += 16) {
    const int f = k0 + skq;
    const int c = f >> 8, py = (f >> 4) & 15, px = f & 15;
    float4 av = make_float4(0.f, 0.f, 0.f, 0.f);
    if (okr) av = *(const float4*)&xbase[((long)c * 224 + py) * 224 + px];
    const float4 wv = *(const float4*)&pw[(k0 + wk) * DM + c0 + wc];
    __syncthreads();
    xs[skq + 0][sr] = av.x; xs[skq + 1][sr] = av.y;
    xs[skq + 2][sr] = av.z; xs[skq + 3][sr] = av.w;
    *(float4*)&wsh[wk][wc] = wv;
    __syncthreads();
    GEMM_FMA_BODY()
  }
  const float4 bv = *(const float4*)&pb[c0 + (tx << 2)];
#pragma unroll
  for (int i = 0; i < 4; i++) {
    const int r = (ty << 2) + i;
    if (r < rows) {
      const int p2 = r0 + r;
      const int b2_ = p2 / 196, n2 = p2 - b2_ * 196;
      const float4 pv = *(const float4*)&pos[(1 + n2) * DM + c0 + (tx << 2)];
      float4 o = make_float4(acc[i][0] + bv.x + pv.x, acc[i][1] + bv.y + pv.y,
                             acc[i][2] + bv.z + pv.z, acc[i][3] + bv.w + pv.w);
      *(float4*)&t[(b2_ * SEQ + 1 + n2) * DM + c0 + (tx << 2)] = o;
    }
  }
}

// MoE phase 1: h[pid] = gelu(t[tok] @ W1_e + b1_e), rows gathered by expert list.
__global__ __launch_bounds__(256) void moe1_kernel(const float* __restrict__ t,
                                                   const float* __restrict__ w1,
                                                   const float* __restrict__ b1,
                                                   const int* __restrict__ lists,
                                                   const int* __restrict__ counts,
                                                   float* __restrict__ h) {
  const int e = blockIdx.y;
  const int n = counts[e];
  const int rt = blockIdx.x;
  if (rt * 64 >= n) return;
  const int ct = blockIdx.z;
  const int rows = min(64, n - rt * 64);
  __shared__ int ent[64];
  __shared__ float xs[16][68];
  __shared__ float wsh[16][68];
  const int tid = threadIdx.x;
  if (tid < 64) ent[tid] = (tid < rows) ? lists[e * CAPE + rt * 64 + tid] : -1;
  const int tx = tid & 15, ty = tid >> 4;
  const int sr = tid >> 2, skq = (tid & 3) << 2;
  const int wk = tid >> 4, wc = (tid & 15) << 2;
  const float* W = w1 + (long)e * DM * HIDN;
  const int c0 = ct * 64;
  __syncthreads();
  const int myrow = ent[sr] >> 1;
  float acc[4][4] = {};
  for (int k0 = 0; k0 < DM; k0 += 16) {
    float4 av = make_float4(0.f, 0.f, 0.f, 0.f);
    if (myrow >= 0) av = *(const float4*)&t[myrow * DM + k0 + skq];
    const float4 wv = *(const float4*)&W[(long)(k0 + wk) * HIDN + c0 + wc];
    __syncthreads();
    xs[skq + 0][sr] = av.x; xs[skq + 1][sr] = av.y;
    xs[skq + 2][sr] = av.z; xs[skq + 3][sr] = av.w;
    *(float4*)&wsh[wk][wc] = wv;
    __syncthreads();
    GEMM_FMA_BODY()
  }
  const float4 bv = *(const float4*)&b1[e * HIDN + c0 + (tx << 2)];
#pragma unroll
  for (int i = 0; i < 4; i++) {
    const int r = (ty << 2) + i;
    if (r < rows) {
      const int pid = ent[r];
      float* hp2 = &h[(long)pid * HIDN + c0 + (tx << 2)];
      hp2[0] = gelu_f(acc[i][0] + bv.x);
      hp2[1] = gelu_f(acc[i][1] + bv.y);
      hp2[2] = gelu_f(acc[i][2] + bv.z);
      hp2[3] = gelu_f(acc[i][3] + bv.w);
    }
  }
}

// MoE phase 2: ybuf[pid] = h[pid] @ W2_e + b2_e
__global__ __launch_bounds__(256) void moe2_kernel(const float* __restrict__ h,
                                                   const float* __restrict__ w2,
                                                   const float* __restrict__ b2,
                                                   const int* __restrict__ lists,
                                                   const int* __restrict__ counts,
                                                   float* __restrict__ ybuf) {
  const int e = blockIdx.y;
  const int n = counts[e];
  const int rt = blockIdx.x;
  if (rt * 64 >= n) return;
  const int ct = blockIdx.z;
  const int rows = min(64, n - rt * 64);
  __shared__ int ent[64];
  __shared__ float xs[16][68];
  __shared__ float wsh[16][68];
  const int tid = threadIdx.x;
  if (tid < 64) ent[tid] = (tid < rows) ? lists[e * CAPE + rt * 64 + tid] : -1;
  const int tx = tid & 15, ty = tid >> 4;
  const int sr = tid >> 2, skq = (tid & 3) << 2;
  const int wk = tid >> 4, wc = (tid & 15) << 2;
  const float* W = w2 + (long)e * HIDN * DM;
  const int c0 = ct * 64;
  __syncthreads();
  const int mypid = ent[sr];
  float acc[4][4] = {};
  for (int k0 = 0; k0 < HIDN; k0 += 16) {
    float4 av = make_float4(0.f, 0.f, 0.f, 0.f);
    if (mypid >= 0) av = *(const float4*)&h[(long)mypid * HIDN + k0 + skq];
    const float4 wv = *(const float4*)&W[(long)(k0 + wk) * DM + c0 + wc];
    __syncthreads();
    xs[skq + 0][sr] = av.x; xs[skq + 1][sr] = av.y;
    xs[skq + 2][sr] = av.z; xs[skq + 3][sr] = av.w;
    *(float4*)&wsh[wk][wc] = wv;
    __syncthreads();
    GEMM_FMA_BODY()
  }
  const float4 bv = *(const float4*)&b2[e * DM + c0 + (tx << 2)];
#pragma unroll
  for (int i = 0; i < 4; i++) {
    const int r = (ty << 2) + i;
    if (r < rows) {
      const int pid = ent[r];
      float4 o = make_float4(acc[i][0] + bv.x, acc[i][1] + bv.y,
                             acc[i][2] + bv.z, acc[i][3] + bv.w);
      *(float4*)&ybuf[(long)pid * DM + c0 + (tx << 2)] = o;
    }
  }
}

__global__ void cls_pos_kernel(const float* __restrict__ cls, const float* __restrict__ pos,
                               float* __restrict__ t) {
  int b = blockIdx.x, d = threadIdx.x;
  t[(b * SEQ) * DM + d] = cls[d] + pos[d];
}

// ---------------- attention: one wave per (b, h, q) ----------------
__global__ __launch_bounds__(64) void attn_kernel(const float* __restrict__ qkv,
                                                  float* __restrict__ out) {
  int bi = blockIdx.x;
  int q = bi % SEQ;
  int bh = bi / SEQ;
  int h = bh % NHEAD, b = bh / NHEAD;
  int lane = threadIdx.x;
  __shared__ float qv[HDIM];
  __shared__ float p[SEQ];
  qv[lane] = qkv[(b * SEQ + q) * 1152 + h * HDIM + lane];
  __syncthreads();
  for (int kt = lane; kt < SEQ; kt += 64) {
    const float* krow = qkv + (b * SEQ + kt) * 1152 + DM + h * HDIM;
    float acc = 0.f;
    for (int d2 = 0; d2 < HDIM; d2++) acc += qv[d2] * krow[d2];
    p[kt] = acc * 0.125f;
  }
  __syncthreads();
  float m = -1e30f;
  for (int kt = lane; kt < SEQ; kt += 64) m = fmaxf(m, p[kt]);
  for (int off = 32; off > 0; off >>= 1) m = fmaxf(m, __shfl_xor(m, off));
  float s = 0.f;
  for (int kt = lane; kt < SEQ; kt += 64) { float e2 = __expf(p[kt] - m); p[kt] = e2; s += e2; }
  for (int off = 32; off > 0; off >>= 1) s += __shfl_xor(s, off);
  float inv = 1.f / s;
  __syncthreads();
  float acc = 0.f;
  for (int kt = 0; kt < SEQ; kt++)
    acc += p[kt] * qkv[(b * SEQ + kt) * 1152 + 2 * DM + h * HDIM + lane];
  out[(b * SEQ + q) * DM + h * HDIM + lane] = acc * inv;
}

// ---------------- residual add + LayerNorm (per token) ----------------
__global__ __launch_bounds__(384) void add_ln_kernel(float* __restrict__ t,
                                                     const float* __restrict__ delta,
                                                     const float* __restrict__ g,
                                                     const float* __restrict__ bta) {
  int tok = blockIdx.x, d = threadIdx.x;
  float v = t[tok * DM + d] + delta[tok * DM + d];
  float sv = v, sq = v * v;
  for (int off = 32; off > 0; off >>= 1) { sv += __shfl_xor(sv, off); sq += __shfl_xor(sq, off); }
  __shared__ float rs[6], rq[6];
  int w = d >> 6, ln = d & 63;
  if (ln == 0) { rs[w] = sv; rq[w] = sq; }
  __syncthreads();
  float mean = 0.f, ms = 0.f;
#pragma unroll
  for (int i = 0; i < 6; i++) { mean += rs[i]; ms += rq[i]; }
  mean *= (1.f / DM); ms *= (1.f / DM);
  float inv = rsqrtf(ms - mean * mean + EPSLN);
  t[tok * DM + d] = (v - mean) * inv * g[d] + bta[d];
}

// ---------------- router logits + top-2: NO global atomics ----------------
// 4 waves/block, one token per wave. Writes idxb/gates only.
__global__ __launch_bounds__(256) void router_logits_kernel(const float* __restrict__ t,
                                                            const float* __restrict__ rw,
                                                            const float* __restrict__ rb,
                                                            unsigned k0, unsigned k1,
                                                            float* __restrict__ gates,
                                                            int* __restrict__ idxb) {
  const int tok = blockIdx.x * 4 + (threadIdx.x >> 6);
  const int lane = threadIdx.x & 63;
  const int e = lane & 7, j = lane >> 3;
  const float* xr = t + tok * DM;
  float acc = 0.f;
  for (int d2 = j * 48; d2 < j * 48 + 48; d2++) acc += xr[d2] * rw[d2 * NEXP + e];
  acc += __shfl_xor(acc, 8);
  acc += __shfl_xor(acc, 16);
  acc += __shfl_xor(acc, 32);
  if (lane < 8) {
    acc += rb[e];
    // JAX threefry_partitionable random_bits: counter=(0,i), bits = y0^y1
    unsigned i = (unsigned)(tok * NEXP + e);
    unsigned y0, y1;
    tf2x32(k0, k1, 0u, i, y0, y1);
    unsigned bits = y0 ^ y1;
    float f = __uint_as_float(0x3f800000u | (bits >> 9)) - 1.0f;
    const float lo = -0.99999994f;
    float u = f * 2.0f + lo;
    u = fmaxf(lo, u);
    acc += 0.01f * (1.41421356f * erfinv32(u));
  }
  float lg[8];
#pragma unroll
  for (int qq = 0; qq < 8; qq++) lg[qq] = __shfl(acc, qq);
  if (lane == 0) {
    int i0 = 0; float v0 = lg[0];
#pragma unroll
    for (int qq = 1; qq < 8; qq++) if (lg[qq] > v0) { v0 = lg[qq]; i0 = qq; }
    int i1 = -1; float v1 = -1e30f;
#pragma unroll
    for (int qq = 0; qq < 8; qq++) if (qq != i0 && lg[qq] > v1) { v1 = lg[qq]; i1 = qq; }
    float e1 = __expf(v1 - v0);
    float g0 = 1.f / (1.f + e1);
    idxb[tok * 2] = i0; idxb[tok * 2 + 1] = i1;
    gates[tok * 2] = g0; gates[tok * 2 + 1] = 1.f - g0;
  }
}

// ---------------- bucket: single block bins all pairs via LDS atomics ----------------
__global__ __launch_bounds__(1024) void bucket_kernel(const int* __restrict__ idxb,
                                                      int* __restrict__ lists,
                                                      int* __restrict__ counts,
                                                      int* __restrict__ occ) {
  __shared__ int lc[NEXP];
  __shared__ int locc[2 * NEXP];
  const int tid = threadIdx.x;
  if (tid < NEXP) lc[tid] = 0;
  if (tid < 2 * NEXP) locc[tid] = 0;
  __syncthreads();
  for (int i = tid; i < 2 * TOK; i += 1024) {
    const int e = idxb[i];
    const int p = atomicAdd(&lc[e], 1);
    lists[e * CAPE + p] = i;
    locc[(i & 1) * NEXP + e] = 1;
  }
  __syncthreads();
  if (tid < NEXP) counts[tid] = lc[tid];
  if (tid < 2 * NEXP) occ[tid] = locc[tid];
}

// ---------------- prep: bias0 = b2 ----------------
__global__ void prep_kernel(const float* __restrict__ b2, float* __restrict__ bias0) {
  int e = blockIdx.x, c = threadIdx.x;
  bias0[e * DM + c] = b2[e * DM + c];
}

// ---------------- bias0 += gelu(b1)@W2 partial over K-chunks ----------------
__global__ __launch_bounds__(384) void bias0_partial_kernel(const float* __restrict__ b1,
                                                            const float* __restrict__ w2,
                                                            float* __restrict__ bias0) {
  const int e = blockIdx.x, kc = blockIdx.y;
  __shared__ float gb[128];
  const int tid = threadIdx.x;
  if (tid < 128) gb[tid] = gelu_f(b1[e * HIDN + kc * 128 + tid]);
  __syncthreads();
  float acc = 0.f;
  const float* W = w2 + ((long)e * HIDN + kc * 128) * DM + tid;
  for (int j2 = 0; j2 < 128; j2++) acc += gb[j2] * W[(long)j2 * DM];
  atomicAdd(&bias0[e * DM + tid], acc);
}

__global__ __launch_bounds__(384) void bias_sum_kernel(const float* __restrict__ bias0,
                                                       const int* __restrict__ occ,
                                                       float* __restrict__ bias_sum) {
  int k = blockIdx.x, d = threadIdx.x;
  float acc = 0.f;
#pragma unroll
  for (int e = 0; e < NEXP; e++)
    if (occ[k * NEXP + e]) acc += bias0[e * DM + d];
  bias_sum[k * DM + d] = acc;
}

// ---------------- combine experts + residual + LN2 ----------------
__global__ __launch_bounds__(384) void moe_combine_ln_kernel(float* __restrict__ t,
                                                             const float* __restrict__ ybuf,
                                                             const float* __restrict__ gates,
                                                             const int* __restrict__ idxb,
                                                             const float* __restrict__ bias0,
                                                             const float* __restrict__ bias_sum,
                                                             const float* __restrict__ g,
                                                             const float* __restrict__ bta) {
  int tok = blockIdx.x, d = threadIdx.x;
  float g0 = gates[tok * 2], g1 = gates[tok * 2 + 1];
  int i0 = idxb[tok * 2], i1 = idxb[tok * 2 + 1];
  float m0 = ybuf[(tok * 2) * DM + d] - bias0[i0 * DM + d] + bias_sum[d];
  float m1 = ybuf[(tok * 2 + 1) * DM + d] - bias0[i1 * DM + d] + bias_sum[DM + d];
  float v = t[tok * DM + d] + g0 * m0 + g1 * m1;
  float sv = v, sq = v * v;
  for (int off = 32; off > 0; off >>= 1) { sv += __shfl_xor(sv, off); sq += __shfl_xor(sq, off); }
  __shared__ float rs[6], rq[6];
  int w = d >> 6, ln = d & 63;
  if (ln == 0) { rs[w] = sv; rq[w] = sq; }
  __syncthreads();
  float mean = 0.f, ms = 0.f;
#pragma unroll
  for (int i = 0; i < 6; i++) { mean += rs[i]; ms += rq[i]; }
  mean *= (1.f / DM); ms *= (1.f / DM);
  float inv = rsqrtf(ms - mean * mean + EPSLN);
  t[tok * DM + d] = (v - mean) * inv * g[d] + bta[d];
}

// ---------------- final: LN(cls) @ fc_w + fc_b, split over col chunks ----------------
__global__ __launch_bounds__(256) void final_kernel(const float* __restrict__ t,
                                                    const float* __restrict__ ng,
                                                    const float* __restrict__ nb,
                                                    const float* __restrict__ fw,
                                                    const float* __restrict__ fb,
                                                    float* __restrict__ out) {
  int b = blockIdx.x, chunk = blockIdx.y, tid = threadIdx.x;
  __shared__ float xr[DM];
  __shared__ float rs[4], rq[4];
  const float* row = t + (b * SEQ) * DM;
  float sv = 0.f, sq = 0.f;
  for (int i = tid; i < DM; i += 256) { float x = row[i]; xr[i] = x; sv += x; sq += x * x; }
  for (int off = 32; off > 0; off >>= 1) { sv += __shfl_xor(sv, off); sq += __shfl_xor(sq, off); }
  int w = tid >> 6, ln = tid & 63;
  if (ln == 0) { rs[w] = sv; rq[w] = sq; }
  __syncthreads();
  float mean = (rs[0] + rs[1] + rs[2] + rs[3]) * (1.f / DM);
  float ms = (rq[0] + rq[1] + rq[2] + rq[3]) * (1.f / DM);
  float inv = rsqrtf(ms - mean * mean + EPSLN);
  for (int i = tid; i < DM; i += 256) xr[i] = (xr[i] - mean) * inv * ng[i] + nb[i];
  __syncthreads();
  int c = chunk * 250 + tid;
  if (tid < 250) {
    float acc = fb[c];
    for (int k = 0; k < DM; k++) acc += xr[k] * fw[k * NCLS + c];
    out[b * NCLS + c] = acc;
  }
}

extern "C" void kernel_launch(void* const* d_in, const int* in_sizes, int n_in,
                              void* d_out, int out_size, void* d_ws, size_t ws_size,
                              hipStream_t stream) {
  const float* x       = (const float*)d_in[0];
  const float* patch_w = (const float*)d_in[1];
  const float* patch_b = (const float*)d_in[2];
  const float* cls_tok = (const float*)d_in[3];
  const float* pos     = (const float*)d_in[4];
  const float* qkv_w   = (const float*)d_in[5];
  const float* qkv_b   = (const float*)d_in[6];
  const float* proj_w  = (const float*)d_in[7];
  const float* proj_b  = (const float*)d_in[8];
  const float* ln1_g   = (const float*)d_in[9];
  const float* ln1_b   = (const float*)d_in[10];
  const float* ln2_g   = (const float*)d_in[11];
  const float* ln2_b   = (const float*)d_in[12];
  const float* router_w = (const float*)d_in[13];
  const float* router_b = (const float*)d_in[14];
  const float* w1      = (const float*)d_in[15];
  const float* b1      = (const float*)d_in[16];
  const float* w2      = (const float*)d_in[17];
  const float* b2      = (const float*)d_in[18];
  const float* norm_g  = (const float*)d_in[19];
  const float* norm_b  = (const float*)d_in[20];
  const float* fc_w    = (const float*)d_in[21];
  const float* fc_b    = (const float*)d_in[22];

  float* ws = (float*)d_ws;
  float* t        = ws;                      // TOK*DM
  float* qkv      = t + TOK * DM;            // TOK*1152
  float* attn     = qkv + TOK * 1152;        // TOK*DM
  float* proj     = attn + TOK * DM;         // TOK*DM
  float* ybuf     = proj + TOK * DM;         // TOK*2*DM
  float* bias0    = ybuf + TOK * 2 * DM;     // NEXP*DM
  float* bias_sum = bias0 + NEXP * DM;       // 2*DM
  float* gates    = bias_sum + 2 * DM;       // TOK*2
  int* idxb   = (int*)(gates + TOK * 2);     // TOK*2
  int* lists  = idxb + TOK * 2;              // NEXP*CAPE
  int* counts = lists + NEXP * CAPE;         // NEXP
  int* occ    = counts + NEXP;               // 2*NEXP
  float* hbuf = (float*)(occ + 2 * NEXP);    // 2*TOK*HIDN  (~19.4 MB)

  patch_gemm_kernel<<<dim3(25, 6), 256, 0, stream>>>(x, patch_w, patch_b, pos, t);
  cls_pos_kernel<<<BATCH, DM, 0, stream>>>(cls_tok, pos, t);

  for (int l = 0; l < LYR; l++) {
    gemm64_kernel<DM, 1152><<<dim3(25, 18), 256, 0, stream>>>(
        t, qkv_w + (long)l * DM * 1152, qkv_b + l * 1152, qkv, TOK);
    attn_kernel<<<BATCH * NHEAD * SEQ, 64, 0, stream>>>(qkv, attn);
    gemm64_kernel<DM, DM><<<dim3(25, 6), 256, 0, stream>>>(
        attn, proj_w + (long)l * DM * DM, proj_b + l * DM, proj, TOK);
    add_ln_kernel<<<TOK, DM, 0, stream>>>(t, proj, ln1_g + l * DM, ln1_b + l * DM);

    prep_kernel<<<NEXP, DM, 0, stream>>>(b2 + l * NEXP * DM, bias0);
    bias0_partial_kernel<<<dim3(NEXP, 12), 384, 0, stream>>>(
        b1 + l * NEXP * HIDN, w2 + (long)l * NEXP * HIDN * DM, bias0);
    unsigned kl0, kl1;
    tf2x32(0u, 42u, 0u, (unsigned)l, kl0, kl1);
    router_logits_kernel<<<TOK / 4, 256, 0, stream>>>(
        t, router_w + l * DM * NEXP, router_b + l * NEXP, kl0, kl1, gates, idxb);
    bucket_kernel<<<1, 1024, 0, stream>>>(idxb, lists, counts, occ);
    bias_sum_kernel<<<2, 384, 0, stream>>>(bias0, occ, bias_sum);
    moe1_kernel<<<dim3(25, NEXP, 24), 256, 0, stream>>>(
        t, w1 + (long)l * NEXP * DM * HIDN, b1 + l * NEXP * HIDN, lists, counts, hbuf);
    moe2_kernel<<<dim3(25, NEXP, 6), 256, 0, stream>>>(
        hbuf, w2 + (long)l * NEXP * HIDN * DM, b2 + l * NEXP * DM, lists, counts, ybuf);
    moe_combine_ln_kernel<<<TOK, DM, 0, stream>>>(t, ybuf, gates, idxb, bias0, bias_sum,
                                                  ln2_g + l * DM, ln2_b + l * DM);
  }

  final_kernel<<<dim3(BATCH, 4), 256, 0, stream>>>(t, norm_g, norm_b, fc_w, fc_b,
                                                   (float*)d_out);
}

// Round 5
// 1268.724 us; speedup vs baseline: 3.5599x; 1.3899x over previous
//
#include <hip/hip_runtime.h>
#include <hip/hip_bf16.h>

constexpr int LYR  = 4;
constexpr int DM   = 384;
constexpr int HIDN = 1536;
constexpr int NHEAD = 6;
constexpr int HDIM = 64;
constexpr int NEXP = 8;
constexpr int SEQ  = 197;
constexpr int BATCH = 8;
constexpr int TOK  = BATCH * SEQ;   // 1576
constexpr int NCLS = 1000;
constexpr int CAPE = TOK;           // max pairs per expert
constexpr int NPATCH = BATCH * 196; // 1568
constexpr float EPSLN = 1e-5f;
constexpr int KP = 40;              // LDS row pitch (bf16 elems): 80B, 16B-aligned, odd bank stride

typedef __attribute__((ext_vector_type(8))) short short8v;
typedef __attribute__((ext_vector_type(4))) float f32x4v;

// ---------------- threefry2x32 (JAX-compatible) ----------------
__host__ __device__ inline void tf2x32(unsigned k0, unsigned k1, unsigned x0, unsigned x1,
                                       unsigned& y0, unsigned& y1) {
  unsigned ks2 = k0 ^ k1 ^ 0x1BD11BDAu;
  unsigned v0 = x0 + k0, v1 = x1 + k1;
#define TFR(r) { v0 += v1; v1 = (v1 << (r)) | (v1 >> (32 - (r))); v1 ^= v0; }
  TFR(13) TFR(15) TFR(26) TFR(6)
  v0 += k1;  v1 += ks2 + 1u;
  TFR(17) TFR(29) TFR(16) TFR(24)
  v0 += ks2; v1 += k0 + 2u;
  TFR(13) TFR(15) TFR(26) TFR(6)
  v0 += k0;  v1 += k1 + 3u;
  TFR(17) TFR(29) TFR(16) TFR(24)
  v0 += k1;  v1 += ks2 + 4u;
  TFR(13) TFR(15) TFR(26) TFR(6)
  v0 += ks2; v1 += k0 + 5u;
#undef TFR
  y0 = v0; y1 = v1;
}

// XLA ErfInv32 (Giles) — matches jax.lax.erf_inv for f32
__device__ inline float erfinv32(float x) {
  float w = -log1pf(-x * x);
  float p;
  if (w < 5.f) {
    w -= 2.5f;
    p = 2.81022636e-08f;
    p = fmaf(p, w, 3.43273939e-07f);
    p = fmaf(p, w, -3.5233877e-06f);
    p = fmaf(p, w, -4.39150654e-06f);
    p = fmaf(p, w, 0.00021858087f);
    p = fmaf(p, w, -0.00125372503f);
    p = fmaf(p, w, -0.00417768164f);
    p = fmaf(p, w, 0.246640727f);
    p = fmaf(p, w, 1.50140941f);
  } else {
    w = sqrtf(w) - 3.f;
    p = -0.000200214257f;
    p = fmaf(p, w, 0.000100950558f);
    p = fmaf(p, w, 0.00134934322f);
    p = fmaf(p, w, -0.00367342844f);
    p = fmaf(p, w, 0.00573950773f);
    p = fmaf(p, w, -0.0076224613f);
    p = fmaf(p, w, 0.00943887047f);
    p = fmaf(p, w, 1.00167406f);
    p = fmaf(p, w, 2.83297682f);
  }
  return p * x;
}

__device__ inline float gelu_f(float x) {
  return 0.5f * x * (1.f + erff(x * 0.70710678118654752f));
}

__device__ inline unsigned short bf16_rne(float x) {
  unsigned u = __float_as_uint(x);
  unsigned r = (u + 0x7fffu + ((u >> 16) & 1u)) >> 16;
  return (unsigned short)r;
}
__device__ inline void split2(float x, short& hs, short& ls) {
  unsigned hu = bf16_rne(x);
  float hf = __uint_as_float(hu << 16);
  unsigned lu = bf16_rne(x - hf);
  hs = (short)hu; ls = (short)lu;
}

// =====================================================================
// Weight pre-conversion: W[K][N] fp32 -> MFMA A-frag chunks, hi/lo bf16.
// Chunk (kt,nt) covers k in [kt*32,kt*32+32), n in [nt*16,nt*16+16).
// Layout: dst[chunk*1024 + lane*8 + j] = hi of W[kt*32+(lane>>4)*8+j][nt*16+(lane&15)]
//         dst[chunk*1024 + 512 + lane*8 + j] = lo. (A-frag: m=lane&15, k=quad*8+j)
// blockIdx.y = expert (or 0).
// =====================================================================
__global__ __launch_bounds__(256) void convw_kernel(const float* __restrict__ src,
                                                    short* __restrict__ dst,
                                                    int K, int N) {
  const int nchunks = (K >> 5) * (N >> 4);
  const int chunk = blockIdx.x * 4 + (threadIdx.x >> 6);
  if (chunk >= nchunks) return;
  const int lane = threadIdx.x & 63;
  const long eoffS = (long)blockIdx.y * K * N;
  const long eoffD = (long)blockIdx.y * nchunks * 1024;
  const int nc = N >> 4;
  const int kt = chunk / nc, nt = chunk - kt * nc;
  const int n = nt * 16 + (lane & 15);
  const int kb = kt * 32 + (lane >> 4) * 8;
  short8v hv, lv;
#pragma unroll
  for (int j = 0; j < 8; j++) {
    short h, l;
    split2(src[eoffS + (long)(kb + j) * N + n], h, l);
    hv[j] = h; lv[j] = l;
  }
  *(short8v*)&dst[eoffD + (long)chunk * 1024 + lane * 8] = hv;
  *(short8v*)&dst[eoffD + (long)chunk * 1024 + 512 + lane * 8] = lv;
}

// =====================================================================
// MFMA GEMM: 64 rows x 64 cols per block, 4 waves (each 32x32 quadrant,
// 2x2 of 16x16x32 mfma), bf16x2-split (3 products), fp32 accumulate.
// W is the A-operand (frag-ordered, direct global loads); X staged to LDS
// as hi/lo planes (k-contiguous). MODE: 0 = dense rows, 1 = moe1 (gather
// token=list>>1, gelu, out row = pid), 2 = moe2 (gather pid, out row = pid).
// =====================================================================
template <int KTOT, int NTOT, int MODE>
__global__ __launch_bounds__(256) void mfma_gemm_kernel(const float* __restrict__ A,
                                                        const short* __restrict__ Wf,
                                                        const float* __restrict__ bias,
                                                        const int* __restrict__ lists,
                                                        const int* __restrict__ counts,
                                                        float* __restrict__ out) {
  const int e = MODE ? blockIdx.y : 0;
  int rowsM;
  if (MODE) {
    const int n = counts[e];
    if ((int)blockIdx.x * 64 >= n) return;
    rowsM = min(64, n - (int)blockIdx.x * 64);
  } else {
    rowsM = min(64, TOK - (int)blockIdx.x * 64);
  }
  const int c0 = blockIdx.z * 64;
  const int tid = threadIdx.x;
  const int w = tid >> 6, lane = tid & 63;
  __shared__ int ent[64];
  __shared__ short xh[64 * KP];
  __shared__ short xl[64 * KP];
  if (MODE) {
    if (tid < 64) ent[tid] = (tid < rowsM) ? lists[e * CAPE + blockIdx.x * 64 + tid] : -1;
    __syncthreads();
  }
  const int sr = tid >> 2, skq = (tid & 3) * 8;
  bool okr; long arow = 0;
  if (MODE == 0) {
    okr = (sr < rowsM);
    arow = (long)(blockIdx.x * 64 + sr) * KTOT;
  } else {
    const int pid = ent[sr];
    okr = (pid >= 0);
    arow = (long)((MODE == 1) ? (pid >> 1) : pid) * KTOT;
  }
  const short* W = Wf + (long)e * (KTOT >> 5) * (NTOT >> 4) * 1024;
  const int wm = (w >> 1) * 32, wn = (w & 1) * 32;
  f32x4v Cr[2][2] = {};  // [token-tile][n-tile]
  float4 ra = make_float4(0.f, 0.f, 0.f, 0.f), rb = ra;
  if (okr) {
    ra = *(const float4*)&A[arow + skq];
    rb = *(const float4*)&A[arow + skq + 4];
  }
  for (int kt = 0; kt < KTOT / 32; ++kt) {
    __syncthreads();  // prior compute done reading LDS
    {
      const float v[8] = {ra.x, ra.y, ra.z, ra.w, rb.x, rb.y, rb.z, rb.w};
      short8v hv, lv;
#pragma unroll
      for (int j = 0; j < 8; j++) { short h, l; split2(v[j], h, l); hv[j] = h; lv[j] = l; }
      *(short8v*)&xh[sr * KP + skq] = hv;
      *(short8v*)&xl[sr * KP + skq] = lv;
    }
    if (kt + 1 < KTOT / 32 && okr) {  // prefetch next tile during compute
      ra = *(const float4*)&A[arow + (kt + 1) * 32 + skq];
      rb = *(const float4*)&A[arow + (kt + 1) * 32 + skq + 4];
    }
    __syncthreads();  // LDS ready
    short8v bhv[2], blv[2];
#pragma unroll
    for (int tt = 0; tt < 2; ++tt) {
      const int trow = wm + tt * 16 + (lane & 15);
      bhv[tt] = *(const short8v*)&xh[trow * KP + (lane >> 4) * 8];
      blv[tt] = *(const short8v*)&xl[trow * KP + (lane >> 4) * 8];
    }
    const long wkb = ((long)kt * (NTOT >> 4) + (c0 >> 4) + (wn >> 4)) * 1024;
#pragma unroll
    for (int nt = 0; nt < 2; ++nt) {
      const short8v wh = *(const short8v*)&W[wkb + nt * 1024 + lane * 8];
      const short8v wl = *(const short8v*)&W[wkb + nt * 1024 + 512 + lane * 8];
#pragma unroll
      for (int tt = 0; tt < 2; ++tt) {
        Cr[tt][nt] = __builtin_amdgcn_mfma_f32_16x16x32_bf16(wh, bhv[tt], Cr[tt][nt], 0, 0, 0);
        Cr[tt][nt] = __builtin_amdgcn_mfma_f32_16x16x32_bf16(wh, blv[tt], Cr[tt][nt], 0, 0, 0);
        Cr[tt][nt] = __builtin_amdgcn_mfma_f32_16x16x32_bf16(wl, bhv[tt], Cr[tt][nt], 0, 0, 0);
      }
    }
  }
  // Epilogue: D lane holds token col = lane&15, n rows = (lane>>4)*4+reg (4 consecutive n)
  const int tl = lane & 15;
  const int nq = (lane >> 4) * 4;
#pragma unroll
  for (int tt = 0; tt < 2; ++tt) {
    const int trow = wm + tt * 16 + tl;
    if (trow < rowsM) {
      long orow;
      if (MODE == 0) orow = (long)(blockIdx.x * 64 + trow) * NTOT;
      else orow = (long)ent[trow] * NTOT;
#pragma unroll
      for (int nt = 0; nt < 2; ++nt) {
        const int n = c0 + wn + nt * 16 + nq;
        const float4 bv = *(const float4*)&bias[(MODE ? e * NTOT : 0) + n];
        float4 o;
        o.x = Cr[tt][nt][0] + bv.x;
        o.y = Cr[tt][nt][1] + bv.y;
        o.z = Cr[tt][nt][2] + bv.z;
        o.w = Cr[tt][nt][3] + bv.w;
        if (MODE == 1) { o.x = gelu_f(o.x); o.y = gelu_f(o.y); o.z = gelu_f(o.z); o.w = gelu_f(o.w); }
        *(float4*)&out[orow + n] = o;
      }
    }
  }
}

// ---------------- patch embed as fp32 GEMM (unchanged) ----------------
#define GEMM_FMA_BODY()                                                     \
  _Pragma("unroll")                                                         \
  for (int k = 0; k < 16; k++) {                                            \
    const float4 a4 = *(const float4*)&xs[k][ty << 2];                      \
    const float4 b4 = *(const float4*)&wsh[k][tx << 2];                     \
    const float aa[4] = {a4.x, a4.y, a4.z, a4.w};                           \
    const float bb[4] = {b4.x, b4.y, b4.z, b4.w};                           \
    _Pragma("unroll")                                                       \
    for (int i = 0; i < 4; i++)                                             \
      _Pragma("unroll")                                                     \
      for (int j = 0; j < 4; j++) acc[i][j] = fmaf(aa[i], bb[j], acc[i][j]);\
  }

__global__ __launch_bounds__(256) void patch_gemm_kernel(const float* __restrict__ x,
                                                         const float* __restrict__ pw,
                                                         const float* __restrict__ pb,
                                                         const float* __restrict__ pos,
                                                         float* __restrict__ t) {
  __shared__ float xs[16][68];
  __shared__ float wsh[16][68];
  const int r0 = blockIdx.x * 64, c0 = blockIdx.y * 64;
  const int rows = min(64, NPATCH - r0);
  const int tid = threadIdx.x;
  const int tx = tid & 15, ty = tid >> 4;
  const int sr = tid >> 2, skq = (tid & 3) << 2;
  const int wk = tid >> 4, wc = (tid & 15) << 2;
  const int p = r0 + sr;
  const bool okr = (sr < rows);
  const int b = p / 196, n = p - b * 196;
  const int hp = n / 14, wp = n - hp * 14;
  const float* xbase = x + ((long)(b * 3) * 224 + hp * 16) * 224 + wp * 16;
  float acc[4][4] = {};
  for (int k0 = 0; k0 < 768; k0 += 16) {
    const int f = k0 + skq;
    const int c = f >> 8, py = (f >> 4) & 15, px = f & 15;
    float4 av = make_float4(0.f, 0.f, 0.f, 0.f);
    if (okr) av = *(const float4*)&xbase[((long)c * 224 + py) * 224 + px];
    const float4 wv = *(const float4*)&pw[(k0 + wk) * DM + c0 + wc];
    __syncthreads();
    xs[skq + 0][sr] = av.x; xs[skq + 1][sr] = av.y;
    xs[skq + 2][sr] = av.z; xs[skq + 3][sr] = av.w;
    *(float4*)&wsh[wk][wc] = wv;
    __syncthreads();
    GEMM_FMA_BODY()
  }
  const float4 bv = *(const float4*)&pb[c0 + (tx << 2)];
#pragma unroll
  for (int i = 0; i < 4; i++) {
    const int r = (ty << 2) + i;
    if (r < rows) {
      const int p2 = r0 + r;
      const int b2_ = p2 / 196, n2 = p2 - b2_ * 196;
      const float4 pv = *(const float4*)&pos[(1 + n2) * DM + c0 + (tx << 2)];
      float4 o = make_float4(acc[i][0] + bv.x + pv.x, acc[i][1] + bv.y + pv.y,
                             acc[i][2] + bv.z + pv.z, acc[i][3] + bv.w + pv.w);
      *(float4*)&t[(b2_ * SEQ + 1 + n2) * DM + c0 + (tx << 2)] = o;
    }
  }
}

__global__ void cls_pos_kernel(const float* __restrict__ cls, const float* __restrict__ pos,
                               float* __restrict__ t) {
  int b = blockIdx.x, d = threadIdx.x;
  t[(b * SEQ) * DM + d] = cls[d] + pos[d];
}

// ---------------- attention: one wave per (b, h, q) ----------------
__global__ __launch_bounds__(64) void attn_kernel(const float* __restrict__ qkv,
                                                  float* __restrict__ out) {
  int bi = blockIdx.x;
  int q = bi % SEQ;
  int bh = bi / SEQ;
  int h = bh % NHEAD, b = bh / NHEAD;
  int lane = threadIdx.x;
  __shared__ float qv[HDIM];
  __shared__ float p[SEQ];
  qv[lane] = qkv[(b * SEQ + q) * 1152 + h * HDIM + lane];
  __syncthreads();
  for (int kt = lane; kt < SEQ; kt += 64) {
    const float* krow = qkv + (b * SEQ + kt) * 1152 + DM + h * HDIM;
    float acc = 0.f;
    for (int d2 = 0; d2 < HDIM; d2++) acc += qv[d2] * krow[d2];
    p[kt] = acc * 0.125f;
  }
  __syncthreads();
  float m = -1e30f;
  for (int kt = lane; kt < SEQ; kt += 64) m = fmaxf(m, p[kt]);
  for (int off = 32; off > 0; off >>= 1) m = fmaxf(m, __shfl_xor(m, off));
  float s = 0.f;
  for (int kt = lane; kt < SEQ; kt += 64) { float e2 = __expf(p[kt] - m); p[kt] = e2; s += e2; }
  for (int off = 32; off > 0; off >>= 1) s += __shfl_xor(s, off);
  float inv = 1.f / s;
  __syncthreads();
  float acc = 0.f;
  for (int kt = 0; kt < SEQ; kt++)
    acc += p[kt] * qkv[(b * SEQ + kt) * 1152 + 2 * DM + h * HDIM + lane];
  out[(b * SEQ + q) * DM + h * HDIM + lane] = acc * inv;
}

// ---------------- residual add + LayerNorm (per token) ----------------
__global__ __launch_bounds__(384) void add_ln_kernel(float* __restrict__ t,
                                                     const float* __restrict__ delta,
                                                     const float* __restrict__ g,
                                                     const float* __restrict__ bta) {
  int tok = blockIdx.x, d = threadIdx.x;
  float v = t[tok * DM + d] + delta[tok * DM + d];
  float sv = v, sq = v * v;
  for (int off = 32; off > 0; off >>= 1) { sv += __shfl_xor(sv, off); sq += __shfl_xor(sq, off); }
  __shared__ float rs[6], rq[6];
  int w = d >> 6, ln = d & 63;
  if (ln == 0) { rs[w] = sv; rq[w] = sq; }
  __syncthreads();
  float mean = 0.f, ms = 0.f;
#pragma unroll
  for (int i = 0; i < 6; i++) { mean += rs[i]; ms += rq[i]; }
  mean *= (1.f / DM); ms *= (1.f / DM);
  float inv = rsqrtf(ms - mean * mean + EPSLN);
  t[tok * DM + d] = (v - mean) * inv * g[d] + bta[d];
}

// ---------------- router logits + top-2 (no global atomics) ----------------
__global__ __launch_bounds__(256) void router_logits_kernel(const float* __restrict__ t,
                                                            const float* __restrict__ rw,
                                                            const float* __restrict__ rb,
                                                            unsigned k0, unsigned k1,
                                                            float* __restrict__ gates,
                                                            int* __restrict__ idxb) {
  const int tok = blockIdx.x * 4 + (threadIdx.x >> 6);
  const int lane = threadIdx.x & 63;
  const int e = lane & 7, j = lane >> 3;
  const float* xr = t + tok * DM;
  float acc = 0.f;
  for (int d2 = j * 48; d2 < j * 48 + 48; d2++) acc += xr[d2] * rw[d2 * NEXP + e];
  acc += __shfl_xor(acc, 8);
  acc += __shfl_xor(acc, 16);
  acc += __shfl_xor(acc, 32);
  if (lane < 8) {
    acc += rb[e];
    // JAX threefry_partitionable random_bits: counter=(0,i), bits = y0^y1
    unsigned i = (unsigned)(tok * NEXP + e);
    unsigned y0, y1;
    tf2x32(k0, k1, 0u, i, y0, y1);
    unsigned bits = y0 ^ y1;
    float f = __uint_as_float(0x3f800000u | (bits >> 9)) - 1.0f;
    const float lo = -0.99999994f;
    float u = f * 2.0f + lo;
    u = fmaxf(lo, u);
    acc += 0.01f * (1.41421356f * erfinv32(u));
  }
  float lg[8];
#pragma unroll
  for (int qq = 0; qq < 8; qq++) lg[qq] = __shfl(acc, qq);
  if (lane == 0) {
    int i0 = 0; float v0 = lg[0];
#pragma unroll
    for (int qq = 1; qq < 8; qq++) if (lg[qq] > v0) { v0 = lg[qq]; i0 = qq; }
    int i1 = -1; float v1 = -1e30f;
#pragma unroll
    for (int qq = 0; qq < 8; qq++) if (qq != i0 && lg[qq] > v1) { v1 = lg[qq]; i1 = qq; }
    float e1 = __expf(v1 - v0);
    float g0 = 1.f / (1.f + e1);
    idxb[tok * 2] = i0; idxb[tok * 2 + 1] = i1;
    gates[tok * 2] = g0; gates[tok * 2 + 1] = 1.f - g0;
  }
}

// ---------------- bucket: single block bins all pairs via LDS atomics ----------------
__global__ __launch_bounds__(1024) void bucket_kernel(const int* __restrict__ idxb,
                                                      int* __restrict__ lists,
                                                      int* __restrict__ counts,
                                                      int* __restrict__ occ) {
  __shared__ int lc[NEXP];
  __shared__ int locc[2 * NEXP];
  const int tid = threadIdx.x;
  if (tid < NEXP) lc[tid] = 0;
  if (tid < 2 * NEXP) locc[tid] = 0;
  __syncthreads();
  for (int i = tid; i < 2 * TOK; i += 1024) {
    const int e = idxb[i];
    const int p = atomicAdd(&lc[e], 1);
    lists[e * CAPE + p] = i;
    locc[(i & 1) * NEXP + e] = 1;
  }
  __syncthreads();
  if (tid < NEXP) counts[tid] = lc[tid];
  if (tid < 2 * NEXP) occ[tid] = locc[tid];
}

// ---------------- prep: bias0 = b2 ----------------
__global__ void prep_kernel(const float* __restrict__ b2, float* __restrict__ bias0) {
  int e = blockIdx.x, c = threadIdx.x;
  bias0[e * DM + c] = b2[e * DM + c];
}

// ---------------- bias0 += gelu(b1)@W2 partial over K-chunks ----------------
__global__ __launch_bounds__(384) void bias0_partial_kernel(const float* __restrict__ b1,
                                                            const float* __restrict__ w2,
                                                            float* __restrict__ bias0) {
  const int e = blockIdx.x, kc = blockIdx.y;
  __shared__ float gb[128];
  const int tid = threadIdx.x;
  if (tid < 128) gb[tid] = gelu_f(b1[e * HIDN + kc * 128 + tid]);
  __syncthreads();
  float acc = 0.f;
  const float* W = w2 + ((long)e * HIDN + kc * 128) * DM + tid;
  for (int j2 = 0; j2 < 128; j2++) acc += gb[j2] * W[(long)j2 * DM];
  atomicAdd(&bias0[e * DM + tid], acc);
}

__global__ __launch_bounds__(384) void bias_sum_kernel(const float* __restrict__ bias0,
                                                       const int* __restrict__ occ,
                                                       float* __restrict__ bias_sum) {
  int k = blockIdx.x, d = threadIdx.x;
  float acc = 0.f;
#pragma unroll
  for (int e = 0; e < NEXP; e++)
    if (occ[k * NEXP + e]) acc += bias0[e * DM + d];
  bias_sum[k * DM + d] = acc;
}

// ---------------- combine experts + residual + LN2 ----------------
__global__ __launch_bounds__(384) void moe_combine_ln_kernel(float* __restrict__ t,
                                                             const float* __restrict__ ybuf,
                                                             const float* __restrict__ gates,
                                                             const int* __restrict__ idxb,
                                                             const float* __restrict__ bias0,
                                                             const float* __restrict__ bias_sum,
                                                             const float* __restrict__ g,
                                                             const float* __restrict__ bta) {
  int tok = blockIdx.x, d = threadIdx.x;
  float g0 = gates[tok * 2], g1 = gates[tok * 2 + 1];
  int i0 = idxb[tok * 2], i1 = idxb[tok * 2 + 1];
  float m0 = ybuf[(tok * 2) * DM + d] - bias0[i0 * DM + d] + bias_sum[d];
  float m1 = ybuf[(tok * 2 + 1) * DM + d] - bias0[i1 * DM + d] + bias_sum[DM + d];
  float v = t[tok * DM + d] + g0 * m0 + g1 * m1;
  float sv = v, sq = v * v;
  for (int off = 32; off > 0; off >>= 1) { sv += __shfl_xor(sv, off); sq += __shfl_xor(sq, off); }
  __shared__ float rs[6], rq[6];
  int w = d >> 6, ln = d & 63;
  if (ln == 0) { rs[w] = sv; rq[w] = sq; }
  __syncthreads();
  float mean = 0.f, ms = 0.f;
#pragma unroll
  for (int i = 0; i < 6; i++) { mean += rs[i]; ms += rq[i]; }
  mean *= (1.f / DM); ms *= (1.f / DM);
  float inv = rsqrtf(ms - mean * mean + EPSLN);
  t[tok * DM + d] = (v - mean) * inv * g[d] + bta[d];
}

// ---------------- final: LN(cls) @ fc_w + fc_b ----------------
__global__ __launch_bounds__(256) void final_kernel(const float* __restrict__ t,
                                                    const float* __restrict__ ng,
                                                    const float* __restrict__ nb,
                                                    const float* __restrict__ fw,
                                                    const float* __restrict__ fb,
                                                    float* __restrict__ out) {
  int b = blockIdx.x, chunk = blockIdx.y, tid = threadIdx.x;
  __shared__ float xr[DM];
  __shared__ float rs[4], rq[4];
  const float* row = t + (b * SEQ) * DM;
  float sv = 0.f, sq = 0.f;
  for (int i = tid; i < DM; i += 256) { float x = row[i]; xr[i] = x; sv += x; sq += x * x; }
  for (int off = 32; off > 0; off >>= 1) { sv += __shfl_xor(sv, off); sq += __shfl_xor(sq, off); }
  int w = tid >> 6, ln = tid & 63;
  if (ln == 0) { rs[w] = sv; rq[w] = sq; }
  __syncthreads();
  float mean = (rs[0] + rs[1] + rs[2] + rs[3]) * (1.f / DM);
  float ms = (rq[0] + rq[1] + rq[2] + rq[3]) * (1.f / DM);
  float inv = rsqrtf(ms - mean * mean + EPSLN);
  for (int i = tid; i < DM; i += 256) xr[i] = (xr[i] - mean) * inv * ng[i] + nb[i];
  __syncthreads();
  int c = chunk * 250 + tid;
  if (tid < 250) {
    float acc = fb[c];
    for (int k = 0; k < DM; k++) acc += xr[k] * fw[k * NCLS + c];
    out[b * NCLS + c] = acc;
  }
}

extern "C" void kernel_launch(void* const* d_in, const int* in_sizes, int n_in,
                              void* d_out, int out_size, void* d_ws, size_t ws_size,
                              hipStream_t stream) {
  const float* x       = (const float*)d_in[0];
  const float* patch_w = (const float*)d_in[1];
  const float* patch_b = (const float*)d_in[2];
  const float* cls_tok = (const float*)d_in[3];
  const float* pos     = (const float*)d_in[4];
  const float* qkv_w   = (const float*)d_in[5];
  const float* qkv_b   = (const float*)d_in[6];
  const float* proj_w  = (const float*)d_in[7];
  const float* proj_b  = (const float*)d_in[8];
  const float* ln1_g   = (const float*)d_in[9];
  const float* ln1_b   = (const float*)d_in[10];
  const float* ln2_g   = (const float*)d_in[11];
  const float* ln2_b   = (const float*)d_in[12];
  const float* router_w = (const float*)d_in[13];
  const float* router_b = (const float*)d_in[14];
  const float* w1      = (const float*)d_in[15];
  const float* b1      = (const float*)d_in[16];
  const float* w2      = (const float*)d_in[17];
  const float* b2      = (const float*)d_in[18];
  const float* norm_g  = (const float*)d_in[19];
  const float* norm_b  = (const float*)d_in[20];
  const float* fc_w    = (const float*)d_in[21];
  const float* fc_b    = (const float*)d_in[22];

  float* ws = (float*)d_ws;
  float* t        = ws;                      // TOK*DM
  float* qkv      = t + TOK * DM;            // TOK*1152
  float* attn     = qkv + TOK * 1152;        // TOK*DM
  float* proj     = attn + TOK * DM;         // TOK*DM
  float* ybuf     = proj + TOK * DM;         // TOK*2*DM
  float* bias0    = ybuf + TOK * 2 * DM;     // NEXP*DM
  float* bias_sum = bias0 + NEXP * DM;       // 2*DM
  float* gates    = bias_sum + 2 * DM;       // TOK*2
  int* idxb   = (int*)(gates + TOK * 2);     // TOK*2
  int* lists  = idxb + TOK * 2;              // NEXP*CAPE
  int* counts = lists + NEXP * CAPE;         // NEXP
  int* occ    = counts + NEXP;               // 2*NEXP
  float* hbuf = (float*)(occ + 2 * NEXP);    // 2*TOK*HIDN (~19.4 MB)
  short* wqf  = (short*)(hbuf + 2 * TOK * HIDN);          // 864*1024
  short* wpf  = wqf + 864 * 1024;                         // 288*1024
  short* w1f  = wpf + 288 * 1024;                         // 8*1152*1024
  short* w2f  = w1f + 8 * 1152 * 1024;                    // 8*1152*1024

  patch_gemm_kernel<<<dim3(25, 6), 256, 0, stream>>>(x, patch_w, patch_b, pos, t);
  cls_pos_kernel<<<BATCH, DM, 0, stream>>>(cls_tok, pos, t);

  for (int l = 0; l < LYR; l++) {
    // weight conversion for this layer (fp32 -> frag-ordered bf16 hi/lo)
    convw_kernel<<<dim3(216, 1), 256, 0, stream>>>(qkv_w + (long)l * DM * 1152, wqf, DM, 1152);
    convw_kernel<<<dim3(72, 1), 256, 0, stream>>>(proj_w + (long)l * DM * DM, wpf, DM, DM);
    convw_kernel<<<dim3(288, NEXP), 256, 0, stream>>>(w1 + (long)l * NEXP * DM * HIDN, w1f, DM, HIDN);
    convw_kernel<<<dim3(288, NEXP), 256, 0, stream>>>(w2 + (long)l * NEXP * HIDN * DM, w2f, HIDN, DM);

    mfma_gemm_kernel<DM, 1152, 0><<<dim3(25, 1, 18), 256, 0, stream>>>(
        t, wqf, qkv_b + l * 1152, nullptr, nullptr, qkv);
    attn_kernel<<<BATCH * NHEAD * SEQ, 64, 0, stream>>>(qkv, attn);
    mfma_gemm_kernel<DM, DM, 0><<<dim3(25, 1, 6), 256, 0, stream>>>(
        attn, wpf, proj_b + l * DM, nullptr, nullptr, proj);
    add_ln_kernel<<<TOK, DM, 0, stream>>>(t, proj, ln1_g + l * DM, ln1_b + l * DM);

    prep_kernel<<<NEXP, DM, 0, stream>>>(b2 + l * NEXP * DM, bias0);
    bias0_partial_kernel<<<dim3(NEXP, 12), 384, 0, stream>>>(
        b1 + l * NEXP * HIDN, w2 + (long)l * NEXP * HIDN * DM, bias0);
    unsigned kl0, kl1;
    tf2x32(0u, 42u, 0u, (unsigned)l, kl0, kl1);
    router_logits_kernel<<<TOK / 4, 256, 0, stream>>>(
        t, router_w + l * DM * NEXP, router_b + l * NEXP, kl0, kl1, gates, idxb);
    bucket_kernel<<<1, 1024, 0, stream>>>(idxb, lists, counts, occ);
    bias_sum_kernel<<<2, 384, 0, stream>>>(bias0, occ, bias_sum);
    mfma_gemm_kernel<DM, HIDN, 1><<<dim3(25, NEXP, 24), 256, 0, stream>>>(
        t, w1f, b1 + l * NEXP * HIDN, lists, counts, hbuf);
    mfma_gemm_kernel<HIDN, DM, 2><<<dim3(25, NEXP, 6), 256, 0, stream>>>(
        hbuf, w2f, b2 + l * NEXP * DM, lists, counts, ybuf);
    moe_combine_ln_kernel<<<TOK, DM, 0, stream>>>(t, ybuf, gates, idxb, bias0, bias_sum,
                                                  ln2_g + l * DM, ln2_b + l * DM);
  }

  final_kernel<<<dim3(BATCH, 4), 256, 0, stream>>>(t, norm_g, norm_b, fc_w, fc_b,
                                                   (float*)d_out);
}

// Round 6
// 963.147 us; speedup vs baseline: 4.6894x; 1.3173x over previous
//
#include <hip/hip_runtime.h>
#include <hip/hip_bf16.h>

constexpr int LYR  = 4;
constexpr int DM   = 384;
constexpr int HIDN = 1536;
constexpr int NHEAD = 6;
constexpr int HDIM = 64;
constexpr int NEXP = 8;
constexpr int SEQ  = 197;
constexpr int BATCH = 8;
constexpr int TOK  = BATCH * SEQ;   // 1576
constexpr int NCLS = 1000;
constexpr int CAPE = TOK;           // max pairs per expert
constexpr int NPATCH = BATCH * 196; // 1568
constexpr float EPSLN = 1e-5f;
constexpr int KP = 40;              // LDS row pitch (bf16 elems) for mfma gemm staging

typedef __attribute__((ext_vector_type(8))) short short8v;
typedef __attribute__((ext_vector_type(4))) float f32x4v;

// ---------------- threefry2x32 (JAX-compatible) ----------------
__host__ __device__ inline void tf2x32(unsigned k0, unsigned k1, unsigned x0, unsigned x1,
                                       unsigned& y0, unsigned& y1) {
  unsigned ks2 = k0 ^ k1 ^ 0x1BD11BDAu;
  unsigned v0 = x0 + k0, v1 = x1 + k1;
#define TFR(r) { v0 += v1; v1 = (v1 << (r)) | (v1 >> (32 - (r))); v1 ^= v0; }
  TFR(13) TFR(15) TFR(26) TFR(6)
  v0 += k1;  v1 += ks2 + 1u;
  TFR(17) TFR(29) TFR(16) TFR(24)
  v0 += ks2; v1 += k0 + 2u;
  TFR(13) TFR(15) TFR(26) TFR(6)
  v0 += k0;  v1 += k1 + 3u;
  TFR(17) TFR(29) TFR(16) TFR(24)
  v0 += k1;  v1 += ks2 + 4u;
  TFR(13) TFR(15) TFR(26) TFR(6)
  v0 += ks2; v1 += k0 + 5u;
#undef TFR
  y0 = v0; y1 = v1;
}

// XLA ErfInv32 (Giles) — matches jax.lax.erf_inv for f32
__device__ inline float erfinv32(float x) {
  float w = -log1pf(-x * x);
  float p;
  if (w < 5.f) {
    w -= 2.5f;
    p = 2.81022636e-08f;
    p = fmaf(p, w, 3.43273939e-07f);
    p = fmaf(p, w, -3.5233877e-06f);
    p = fmaf(p, w, -4.39150654e-06f);
    p = fmaf(p, w, 0.00021858087f);
    p = fmaf(p, w, -0.00125372503f);
    p = fmaf(p, w, -0.00417768164f);
    p = fmaf(p, w, 0.246640727f);
    p = fmaf(p, w, 1.50140941f);
  } else {
    w = sqrtf(w) - 3.f;
    p = -0.000200214257f;
    p = fmaf(p, w, 0.000100950558f);
    p = fmaf(p, w, 0.00134934322f);
    p = fmaf(p, w, -0.00367342844f);
    p = fmaf(p, w, 0.00573950773f);
    p = fmaf(p, w, -0.0076224613f);
    p = fmaf(p, w, 0.00943887047f);
    p = fmaf(p, w, 1.00167406f);
    p = fmaf(p, w, 2.83297682f);
  }
  return p * x;
}

__device__ inline float gelu_f(float x) {
  return 0.5f * x * (1.f + erff(x * 0.70710678118654752f));
}

__device__ inline unsigned short bf16_rne(float x) {
  unsigned u = __float_as_uint(x);
  unsigned r = (u + 0x7fffu + ((u >> 16) & 1u)) >> 16;
  return (unsigned short)r;
}
__device__ inline void split2(float x, short& hs, short& ls) {
  unsigned hu = bf16_rne(x);
  float hf = __uint_as_float(hu << 16);
  unsigned lu = bf16_rne(x - hf);
  hs = (short)hu; ls = (short)lu;
}

// =====================================================================
// Weight pre-conversion: W[K][N] fp32 -> MFMA A-frag chunks, hi/lo bf16.
// =====================================================================
__global__ __launch_bounds__(256) void convw_kernel(const float* __restrict__ src,
                                                    short* __restrict__ dst,
                                                    int K, int N) {
  const int nchunks = (K >> 5) * (N >> 4);
  const int chunk = blockIdx.x * 4 + (threadIdx.x >> 6);
  if (chunk >= nchunks) return;
  const int lane = threadIdx.x & 63;
  const long eoffS = (long)blockIdx.y * K * N;
  const long eoffD = (long)blockIdx.y * nchunks * 1024;
  const int nc = N >> 4;
  const int kt = chunk / nc, nt = chunk - kt * nc;
  const int n = nt * 16 + (lane & 15);
  const int kb = kt * 32 + (lane >> 4) * 8;
  short8v hv, lv;
#pragma unroll
  for (int j = 0; j < 8; j++) {
    short h, l;
    split2(src[eoffS + (long)(kb + j) * N + n], h, l);
    hv[j] = h; lv[j] = l;
  }
  *(short8v*)&dst[eoffD + (long)chunk * 1024 + lane * 8] = hv;
  *(short8v*)&dst[eoffD + (long)chunk * 1024 + 512 + lane * 8] = lv;
}

// =====================================================================
// MFMA GEMM (bf16x2-split, fp32 accum). MODE: 0 dense, 1 moe1, 2 moe2.
// =====================================================================
template <int KTOT, int NTOT, int MODE>
__global__ __launch_bounds__(256) void mfma_gemm_kernel(const float* __restrict__ A,
                                                        const short* __restrict__ Wf,
                                                        const float* __restrict__ bias,
                                                        const int* __restrict__ lists,
                                                        const int* __restrict__ counts,
                                                        float* __restrict__ out) {
  const int e = MODE ? blockIdx.y : 0;
  int rowsM;
  if (MODE) {
    const int n = counts[e];
    if ((int)blockIdx.x * 64 >= n) return;
    rowsM = min(64, n - (int)blockIdx.x * 64);
  } else {
    rowsM = min(64, TOK - (int)blockIdx.x * 64);
  }
  const int c0 = blockIdx.z * 64;
  const int tid = threadIdx.x;
  const int w = tid >> 6, lane = tid & 63;
  __shared__ int ent[64];
  __shared__ short xh[64 * KP];
  __shared__ short xl[64 * KP];
  if (MODE) {
    if (tid < 64) ent[tid] = (tid < rowsM) ? lists[e * CAPE + blockIdx.x * 64 + tid] : -1;
    __syncthreads();
  }
  const int sr = tid >> 2, skq = (tid & 3) * 8;
  bool okr; long arow = 0;
  if (MODE == 0) {
    okr = (sr < rowsM);
    arow = (long)(blockIdx.x * 64 + sr) * KTOT;
  } else {
    const int pid = ent[sr];
    okr = (pid >= 0);
    arow = (long)((MODE == 1) ? (pid >> 1) : pid) * KTOT;
  }
  const short* W = Wf + (long)e * (KTOT >> 5) * (NTOT >> 4) * 1024;
  const int wm = (w >> 1) * 32, wn = (w & 1) * 32;
  f32x4v Cr[2][2] = {};
  float4 ra = make_float4(0.f, 0.f, 0.f, 0.f), rb = ra;
  if (okr) {
    ra = *(const float4*)&A[arow + skq];
    rb = *(const float4*)&A[arow + skq + 4];
  }
  for (int kt = 0; kt < KTOT / 32; ++kt) {
    __syncthreads();
    {
      const float v[8] = {ra.x, ra.y, ra.z, ra.w, rb.x, rb.y, rb.z, rb.w};
      short8v hv, lv;
#pragma unroll
      for (int j = 0; j < 8; j++) { short h, l; split2(v[j], h, l); hv[j] = h; lv[j] = l; }
      *(short8v*)&xh[sr * KP + skq] = hv;
      *(short8v*)&xl[sr * KP + skq] = lv;
    }
    if (kt + 1 < KTOT / 32 && okr) {
      ra = *(const float4*)&A[arow + (kt + 1) * 32 + skq];
      rb = *(const float4*)&A[arow + (kt + 1) * 32 + skq + 4];
    }
    __syncthreads();
    short8v bhv[2], blv[2];
#pragma unroll
    for (int tt = 0; tt < 2; ++tt) {
      const int trow = wm + tt * 16 + (lane & 15);
      bhv[tt] = *(const short8v*)&xh[trow * KP + (lane >> 4) * 8];
      blv[tt] = *(const short8v*)&xl[trow * KP + (lane >> 4) * 8];
    }
    const long wkb = ((long)kt * (NTOT >> 4) + (c0 >> 4) + (wn >> 4)) * 1024;
#pragma unroll
    for (int nt = 0; nt < 2; ++nt) {
      const short8v wh = *(const short8v*)&W[wkb + nt * 1024 + lane * 8];
      const short8v wl = *(const short8v*)&W[wkb + nt * 1024 + 512 + lane * 8];
#pragma unroll
      for (int tt = 0; tt < 2; ++tt) {
        Cr[tt][nt] = __builtin_amdgcn_mfma_f32_16x16x32_bf16(wh, bhv[tt], Cr[tt][nt], 0, 0, 0);
        Cr[tt][nt] = __builtin_amdgcn_mfma_f32_16x16x32_bf16(wh, blv[tt], Cr[tt][nt], 0, 0, 0);
        Cr[tt][nt] = __builtin_amdgcn_mfma_f32_16x16x32_bf16(wl, bhv[tt], Cr[tt][nt], 0, 0, 0);
      }
    }
  }
  const int tl = lane & 15;
  const int nq = (lane >> 4) * 4;
#pragma unroll
  for (int tt = 0; tt < 2; ++tt) {
    const int trow = wm + tt * 16 + tl;
    if (trow < rowsM) {
      long orow;
      if (MODE == 0) orow = (long)(blockIdx.x * 64 + trow) * NTOT;
      else orow = (long)ent[trow] * NTOT;
#pragma unroll
      for (int nt = 0; nt < 2; ++nt) {
        const int n = c0 + wn + nt * 16 + nq;
        const float4 bv = *(const float4*)&bias[(MODE ? e * NTOT : 0) + n];
        float4 o;
        o.x = Cr[tt][nt][0] + bv.x;
        o.y = Cr[tt][nt][1] + bv.y;
        o.z = Cr[tt][nt][2] + bv.z;
        o.w = Cr[tt][nt][3] + bv.w;
        if (MODE == 1) { o.x = gelu_f(o.x); o.y = gelu_f(o.y); o.z = gelu_f(o.z); o.w = gelu_f(o.w); }
        *(float4*)&out[orow + n] = o;
      }
    }
  }
}

// ---------------- patch embed as fp32 GEMM ----------------
#define GEMM_FMA_BODY()                                                     \
  _Pragma("unroll")                                                         \
  for (int k = 0; k < 16; k++) {                                            \
    const float4 a4 = *(const float4*)&xs[k][ty << 2];                      \
    const float4 b4 = *(const float4*)&wsh[k][tx << 2];                     \
    const float aa[4] = {a4.x, a4.y, a4.z, a4.w};                           \
    const float bb[4] = {b4.x, b4.y, b4.z, b4.w};                           \
    _Pragma("unroll")                                                       \
    for (int i = 0; i < 4; i++)                                             \
      _Pragma("unroll")                                                     \
      for (int j = 0; j < 4; j++) acc[i][j] = fmaf(aa[i], bb[j], acc[i][j]);\
  }

__global__ __launch_bounds__(256) void patch_gemm_kernel(const float* __restrict__ x,
                                                         const float* __restrict__ pw,
                                                         const float* __restrict__ pb,
                                                         const float* __restrict__ pos,
                                                         float* __restrict__ t) {
  __shared__ float xs[16][68];
  __shared__ float wsh[16][68];
  const int r0 = blockIdx.x * 64, c0 = blockIdx.y * 64;
  const int rows = min(64, NPATCH - r0);
  const int tid = threadIdx.x;
  const int tx = tid & 15, ty = tid >> 4;
  const int sr = tid >> 2, skq = (tid & 3) << 2;
  const int wk = tid >> 4, wc = (tid & 15) << 2;
  const int p = r0 + sr;
  const bool okr = (sr < rows);
  const int b = p / 196, n = p - b * 196;
  const int hp = n / 14, wp = n - hp * 14;
  const float* xbase = x + ((long)(b * 3) * 224 + hp * 16) * 224 + wp * 16;
  float acc[4][4] = {};
  for (int k0 = 0; k0 < 768; k0 += 16) {
    const int f = k0 + skq;
    const int c = f >> 8, py = (f >> 4) & 15, px = f & 15;
    float4 av = make_float4(0.f, 0.f, 0.f, 0.f);
    if (okr) av = *(const float4*)&xbase[((long)c * 224 + py) * 224 + px];
    const float4 wv = *(const float4*)&pw[(k0 + wk) * DM + c0 + wc];
    __syncthreads();
    xs[skq + 0][sr] = av.x; xs[skq + 1][sr] = av.y;
    xs[skq + 2][sr] = av.z; xs[skq + 3][sr] = av.w;
    *(float4*)&wsh[wk][wc] = wv;
    __syncthreads();
    GEMM_FMA_BODY()
  }
  const float4 bv = *(const float4*)&pb[c0 + (tx << 2)];
#pragma unroll
  for (int i = 0; i < 4; i++) {
    const int r = (ty << 2) + i;
    if (r < rows) {
      const int p2 = r0 + r;
      const int b2_ = p2 / 196, n2 = p2 - b2_ * 196;
      const float4 pv = *(const float4*)&pos[(1 + n2) * DM + c0 + (tx << 2)];
      float4 o = make_float4(acc[i][0] + bv.x + pv.x, acc[i][1] + bv.y + pv.y,
                             acc[i][2] + bv.z + pv.z, acc[i][3] + bv.w + pv.w);
      *(float4*)&t[(b2_ * SEQ + 1 + n2) * DM + c0 + (tx << 2)] = o;
    }
  }
}

__global__ void cls_pos_kernel(const float* __restrict__ cls, const float* __restrict__ pos,
                               float* __restrict__ t) {
  int b = blockIdx.x, d = threadIdx.x;
  t[(b * SEQ) * DM + d] = cls[d] + pos[d];
}

// =====================================================================
// Tiled attention: one block per (b, h, 32-query tile). Two-pass softmax.
// Phase 1: S = Q@K^T * 0.125 into LDS (K-tiles staged transposed).
// Phase 2: per-row softmax (8 lanes/row, shfl reduce).
// Phase 3: O = P@V (V-tiles staged, reusing K buffer).
// =====================================================================
constexpr int QT = 32;   // queries per block
constexpr int SP = 208;  // S row pitch
__global__ __launch_bounds__(256) void attn_tile_kernel(const float* __restrict__ qkv,
                                                        float* __restrict__ out) {
  const int bh = blockIdx.x;
  const int b = bh / NHEAD, h = bh % NHEAD;
  const int q0 = blockIdx.y * QT;
  const int nq = min(QT, SEQ - q0);
  __shared__ float Qs[64][QT + 4];   // d-major
  __shared__ float KV[64][68];       // phase1: KT[d][key]; phase3: Vs[key][d]
  __shared__ float Ss[QT][SP];
  const int tid = threadIdx.x;
  const int tx = tid & 15, ty = tid >> 4;
  // stage Q (transposed): 32 q x 64 d
  for (int i = tid; i < QT * 16; i += 256) {
    const int q = i >> 4, dq = (i & 15) << 2;
    float4 v = make_float4(0.f, 0.f, 0.f, 0.f);
    if (q < nq) v = *(const float4*)&qkv[(long)(b * SEQ + q0 + q) * 1152 + h * HDIM + dq];
    Qs[dq + 0][q] = v.x; Qs[dq + 1][q] = v.y; Qs[dq + 2][q] = v.z; Qs[dq + 3][q] = v.w;
  }
  // ---- phase 1: scores ----
  for (int kt = 0; kt < 4; ++kt) {
    const int kbase = kt * 64;
    __syncthreads();
    for (int i = tid; i < 64 * 16; i += 256) {
      const int key = i >> 4, dq = (i & 15) << 2;
      float4 v = make_float4(0.f, 0.f, 0.f, 0.f);
      if (kbase + key < SEQ)
        v = *(const float4*)&qkv[(long)(b * SEQ + kbase + key) * 1152 + DM + h * HDIM + dq];
      KV[dq + 0][key] = v.x; KV[dq + 1][key] = v.y; KV[dq + 2][key] = v.z; KV[dq + 3][key] = v.w;
    }
    __syncthreads();
    float acc[2][4] = {};
#pragma unroll 16
    for (int d = 0; d < 64; ++d) {
      const float4 k4 = *(const float4*)&KV[d][tx << 2];
      const float a0 = Qs[d][ty * 2], a1 = Qs[d][ty * 2 + 1];
      const float kk[4] = {k4.x, k4.y, k4.z, k4.w};
#pragma unroll
      for (int j = 0; j < 4; j++) {
        acc[0][j] = fmaf(a0, kk[j], acc[0][j]);
        acc[1][j] = fmaf(a1, kk[j], acc[1][j]);
      }
    }
#pragma unroll
    for (int i = 0; i < 2; i++) {
      float4 o = make_float4(acc[i][0] * 0.125f, acc[i][1] * 0.125f,
                             acc[i][2] * 0.125f, acc[i][3] * 0.125f);
      *(float4*)&Ss[ty * 2 + i][kbase + (tx << 2)] = o;
    }
  }
  __syncthreads();
  // ---- phase 2: softmax per row (8 lanes/row) ----
  {
    const int row = tid >> 3, c = tid & 7;
    float m = -1e30f;
    for (int k = c; k < SEQ; k += 8) m = fmaxf(m, Ss[row][k]);
    m = fmaxf(m, __shfl_xor(m, 1)); m = fmaxf(m, __shfl_xor(m, 2)); m = fmaxf(m, __shfl_xor(m, 4));
    float s = 0.f;
    for (int k = c; k < SEQ; k += 8) { float e2 = __expf(Ss[row][k] - m); Ss[row][k] = e2; s += e2; }
    s += __shfl_xor(s, 1); s += __shfl_xor(s, 2); s += __shfl_xor(s, 4);
    const float inv = 1.f / s;
    for (int k = c; k < SEQ; k += 8) Ss[row][k] *= inv;
  }
  // ---- phase 3: O = P@V ----
  float acc[2][4] = {};
  for (int kt = 0; kt < 4; ++kt) {
    const int kbase = kt * 64;
    const int kend = min(64, SEQ - kbase);
    __syncthreads();
    for (int i = tid; i < 64 * 16; i += 256) {
      const int key = i >> 4, dq = (i & 15) << 2;
      float4 v = make_float4(0.f, 0.f, 0.f, 0.f);
      if (kbase + key < SEQ)
        v = *(const float4*)&qkv[(long)(b * SEQ + kbase + key) * 1152 + 2 * DM + h * HDIM + dq];
      *(float4*)&KV[key][dq] = v;
    }
    __syncthreads();
    for (int k = 0; k < kend; ++k) {
      const float4 v4 = *(const float4*)&KV[k][tx << 2];
      const float p0 = Ss[ty * 2][kbase + k], p1 = Ss[ty * 2 + 1][kbase + k];
      const float vv[4] = {v4.x, v4.y, v4.z, v4.w};
#pragma unroll
      for (int j = 0; j < 4; j++) {
        acc[0][j] = fmaf(p0, vv[j], acc[0][j]);
        acc[1][j] = fmaf(p1, vv[j], acc[1][j]);
      }
    }
  }
#pragma unroll
  for (int i = 0; i < 2; i++) {
    const int row = ty * 2 + i;
    if (row < nq) {
      float4 o = make_float4(acc[i][0], acc[i][1], acc[i][2], acc[i][3]);
      *(float4*)&out[(long)(b * SEQ + q0 + row) * DM + h * HDIM + (tx << 2)] = o;
    }
  }
}

// ---------------- residual add + LayerNorm (per token) ----------------
__global__ __launch_bounds__(384) void add_ln_kernel(float* __restrict__ t,
                                                     const float* __restrict__ delta,
                                                     const float* __restrict__ g,
                                                     const float* __restrict__ bta) {
  int tok = blockIdx.x, d = threadIdx.x;
  float v = t[tok * DM + d] + delta[tok * DM + d];
  float sv = v, sq = v * v;
  for (int off = 32; off > 0; off >>= 1) { sv += __shfl_xor(sv, off); sq += __shfl_xor(sq, off); }
  __shared__ float rs[6], rq[6];
  int w = d >> 6, ln = d & 63;
  if (ln == 0) { rs[w] = sv; rq[w] = sq; }
  __syncthreads();
  float mean = 0.f, ms = 0.f;
#pragma unroll
  for (int i = 0; i < 6; i++) { mean += rs[i]; ms += rq[i]; }
  mean *= (1.f / DM); ms *= (1.f / DM);
  float inv = rsqrtf(ms - mean * mean + EPSLN);
  t[tok * DM + d] = (v - mean) * inv * g[d] + bta[d];
}

// ---------------- router logits + top-2 (no global atomics) ----------------
__global__ __launch_bounds__(256) void router_logits_kernel(const float* __restrict__ t,
                                                            const float* __restrict__ rw,
                                                            const float* __restrict__ rb,
                                                            unsigned k0, unsigned k1,
                                                            float* __restrict__ gates,
                                                            int* __restrict__ idxb) {
  const int tok = blockIdx.x * 4 + (threadIdx.x >> 6);
  const int lane = threadIdx.x & 63;
  const int e = lane & 7, j = lane >> 3;
  const float* xr = t + tok * DM;
  float acc = 0.f;
  for (int d2 = j * 48; d2 < j * 48 + 48; d2++) acc += xr[d2] * rw[d2 * NEXP + e];
  acc += __shfl_xor(acc, 8);
  acc += __shfl_xor(acc, 16);
  acc += __shfl_xor(acc, 32);
  if (lane < 8) {
    acc += rb[e];
    unsigned i = (unsigned)(tok * NEXP + e);
    unsigned y0, y1;
    tf2x32(k0, k1, 0u, i, y0, y1);
    unsigned bits = y0 ^ y1;
    float f = __uint_as_float(0x3f800000u | (bits >> 9)) - 1.0f;
    const float lo = -0.99999994f;
    float u = f * 2.0f + lo;
    u = fmaxf(lo, u);
    acc += 0.01f * (1.41421356f * erfinv32(u));
  }
  float lg[8];
#pragma unroll
  for (int qq = 0; qq < 8; qq++) lg[qq] = __shfl(acc, qq);
  if (lane == 0) {
    int i0 = 0; float v0 = lg[0];
#pragma unroll
    for (int qq = 1; qq < 8; qq++) if (lg[qq] > v0) { v0 = lg[qq]; i0 = qq; }
    int i1 = -1; float v1 = -1e30f;
#pragma unroll
    for (int qq = 0; qq < 8; qq++) if (qq != i0 && lg[qq] > v1) { v1 = lg[qq]; i1 = qq; }
    float e1 = __expf(v1 - v0);
    float g0 = 1.f / (1.f + e1);
    idxb[tok * 2] = i0; idxb[tok * 2 + 1] = i1;
    gates[tok * 2] = g0; gates[tok * 2 + 1] = 1.f - g0;
  }
}

// ---------------- bucket: single block bins all pairs via LDS atomics ----------------
__global__ __launch_bounds__(1024) void bucket_kernel(const int* __restrict__ idxb,
                                                      int* __restrict__ lists,
                                                      int* __restrict__ counts,
                                                      int* __restrict__ occ) {
  __shared__ int lc[NEXP];
  __shared__ int locc[2 * NEXP];
  const int tid = threadIdx.x;
  if (tid < NEXP) lc[tid] = 0;
  if (tid < 2 * NEXP) locc[tid] = 0;
  __syncthreads();
  for (int i = tid; i < 2 * TOK; i += 1024) {
    const int e = idxb[i];
    const int p = atomicAdd(&lc[e], 1);
    lists[e * CAPE + p] = i;
    locc[(i & 1) * NEXP + e] = 1;
  }
  __syncthreads();
  if (tid < NEXP) counts[tid] = lc[tid];
  if (tid < 2 * NEXP) occ[tid] = locc[tid];
}

// ---------------- prep: bias0 = b2 ----------------
__global__ void prep_kernel(const float* __restrict__ b2, float* __restrict__ bias0) {
  int e = blockIdx.x, c = threadIdx.x;
  bias0[e * DM + c] = b2[e * DM + c];
}

// ---------------- bias0 += gelu(b1)@W2 partial over K-chunks ----------------
__global__ __launch_bounds__(384) void bias0_partial_kernel(const float* __restrict__ b1,
                                                            const float* __restrict__ w2,
                                                            float* __restrict__ bias0) {
  const int e = blockIdx.x, kc = blockIdx.y;
  __shared__ float gb[128];
  const int tid = threadIdx.x;
  if (tid < 128) gb[tid] = gelu_f(b1[e * HIDN + kc * 128 + tid]);
  __syncthreads();
  float acc = 0.f;
  const float* W = w2 + ((long)e * HIDN + kc * 128) * DM + tid;
  for (int j2 = 0; j2 < 128; j2++) acc += gb[j2] * W[(long)j2 * DM];
  atomicAdd(&bias0[e * DM + tid], acc);
}

__global__ __launch_bounds__(384) void bias_sum_kernel(const float* __restrict__ bias0,
                                                       const int* __restrict__ occ,
                                                       float* __restrict__ bias_sum) {
  int k = blockIdx.x, d = threadIdx.x;
  float acc = 0.f;
#pragma unroll
  for (int e = 0; e < NEXP; e++)
    if (occ[k * NEXP + e]) acc += bias0[e * DM + d];
  bias_sum[k * DM + d] = acc;
}

// ---------------- combine experts + residual + LN2 ----------------
__global__ __launch_bounds__(384) void moe_combine_ln_kernel(float* __restrict__ t,
                                                             const float* __restrict__ ybuf,
                                                             const float* __restrict__ gates,
                                                             const int* __restrict__ idxb,
                                                             const float* __restrict__ bias0,
                                                             const float* __restrict__ bias_sum,
                                                             const float* __restrict__ g,
                                                             const float* __restrict__ bta) {
  int tok = blockIdx.x, d = threadIdx.x;
  float g0 = gates[tok * 2], g1 = gates[tok * 2 + 1];
  int i0 = idxb[tok * 2], i1 = idxb[tok * 2 + 1];
  float m0 = ybuf[(tok * 2) * DM + d] - bias0[i0 * DM + d] + bias_sum[d];
  float m1 = ybuf[(tok * 2 + 1) * DM + d] - bias0[i1 * DM + d] + bias_sum[DM + d];
  float v = t[tok * DM + d] + g0 * m0 + g1 * m1;
  float sv = v, sq = v * v;
  for (int off = 32; off > 0; off >>= 1) { sv += __shfl_xor(sv, off); sq += __shfl_xor(sq, off); }
  __shared__ float rs[6], rq[6];
  int w = d >> 6, ln = d & 63;
  if (ln == 0) { rs[w] = sv; rq[w] = sq; }
  __syncthreads();
  float mean = 0.f, ms = 0.f;
#pragma unroll
  for (int i = 0; i < 6; i++) { mean += rs[i]; ms += rq[i]; }
  mean *= (1.f / DM); ms *= (1.f / DM);
  float inv = rsqrtf(ms - mean * mean + EPSLN);
  t[tok * DM + d] = (v - mean) * inv * g[d] + bta[d];
}

// ---------------- final: LN(cls) @ fc_w + fc_b ----------------
__global__ __launch_bounds__(256) void final_kernel(const float* __restrict__ t,
                                                    const float* __restrict__ ng,
                                                    const float* __restrict__ nb,
                                                    const float* __restrict__ fw,
                                                    const float* __restrict__ fb,
                                                    float* __restrict__ out) {
  int b = blockIdx.x, chunk = blockIdx.y, tid = threadIdx.x;
  __shared__ float xr[DM];
  __shared__ float rs[4], rq[4];
  const float* row = t + (b * SEQ) * DM;
  float sv = 0.f, sq = 0.f;
  for (int i = tid; i < DM; i += 256) { float x = row[i]; xr[i] = x; sv += x; sq += x * x; }
  for (int off = 32; off > 0; off >>= 1) { sv += __shfl_xor(sv, off); sq += __shfl_xor(sq, off); }
  int w = tid >> 6, ln = tid & 63;
  if (ln == 0) { rs[w] = sv; rq[w] = sq; }
  __syncthreads();
  float mean = (rs[0] + rs[1] + rs[2] + rs[3]) * (1.f / DM);
  float ms = (rq[0] + rq[1] + rq[2] + rq[3]) * (1.f / DM);
  float inv = rsqrtf(ms - mean * mean + EPSLN);
  for (int i = tid; i < DM; i += 256) xr[i] = (xr[i] - mean) * inv * ng[i] + nb[i];
  __syncthreads();
  int c = chunk * 250 + tid;
  if (tid < 250) {
    float acc = fb[c];
    for (int k = 0; k < DM; k++) acc += xr[k] * fw[k * NCLS + c];
    out[b * NCLS + c] = acc;
  }
}

extern "C" void kernel_launch(void* const* d_in, const int* in_sizes, int n_in,
                              void* d_out, int out_size, void* d_ws, size_t ws_size,
                              hipStream_t stream) {
  const float* x       = (const float*)d_in[0];
  const float* patch_w = (const float*)d_in[1];
  const float* patch_b = (const float*)d_in[2];
  const float* cls_tok = (const float*)d_in[3];
  const float* pos     = (const float*)d_in[4];
  const float* qkv_w   = (const float*)d_in[5];
  const float* qkv_b   = (const float*)d_in[6];
  const float* proj_w  = (const float*)d_in[7];
  const float* proj_b  = (const float*)d_in[8];
  const float* ln1_g   = (const float*)d_in[9];
  const float* ln1_b   = (const float*)d_in[10];
  const float* ln2_g   = (const float*)d_in[11];
  const float* ln2_b   = (const float*)d_in[12];
  const float* router_w = (const float*)d_in[13];
  const float* router_b = (const float*)d_in[14];
  const float* w1      = (const float*)d_in[15];
  const float* b1      = (const float*)d_in[16];
  const float* w2      = (const float*)d_in[17];
  const float* b2      = (const float*)d_in[18];
  const float* norm_g  = (const float*)d_in[19];
  const float* norm_b  = (const float*)d_in[20];
  const float* fc_w    = (const float*)d_in[21];
  const float* fc_b    = (const float*)d_in[22];

  float* ws = (float*)d_ws;
  float* t        = ws;                      // TOK*DM
  float* qkv      = t + TOK * DM;            // TOK*1152
  float* attn     = qkv + TOK * 1152;        // TOK*DM
  float* proj     = attn + TOK * DM;         // TOK*DM
  float* ybuf     = proj + TOK * DM;         // TOK*2*DM
  float* bias0    = ybuf + TOK * 2 * DM;     // NEXP*DM
  float* bias_sum = bias0 + NEXP * DM;       // 2*DM
  float* gates    = bias_sum + 2 * DM;       // TOK*2
  int* idxb   = (int*)(gates + TOK * 2);     // TOK*2
  int* lists  = idxb + TOK * 2;              // NEXP*CAPE
  int* counts = lists + NEXP * CAPE;         // NEXP
  int* occ    = counts + NEXP;               // 2*NEXP
  float* hbuf = (float*)(occ + 2 * NEXP);    // 2*TOK*HIDN (~19.4 MB)
  short* wqf  = (short*)(hbuf + 2 * TOK * HIDN);          // 864*1024
  short* wpf  = wqf + 864 * 1024;                         // 288*1024
  short* w1f  = wpf + 288 * 1024;                         // 8*1152*1024
  short* w2f  = w1f + 8 * 1152 * 1024;                    // 8*1152*1024

  patch_gemm_kernel<<<dim3(25, 6), 256, 0, stream>>>(x, patch_w, patch_b, pos, t);
  cls_pos_kernel<<<BATCH, DM, 0, stream>>>(cls_tok, pos, t);

  for (int l = 0; l < LYR; l++) {
    convw_kernel<<<dim3(216, 1), 256, 0, stream>>>(qkv_w + (long)l * DM * 1152, wqf, DM, 1152);
    convw_kernel<<<dim3(72, 1), 256, 0, stream>>>(proj_w + (long)l * DM * DM, wpf, DM, DM);
    convw_kernel<<<dim3(288, NEXP), 256, 0, stream>>>(w1 + (long)l * NEXP * DM * HIDN, w1f, DM, HIDN);
    convw_kernel<<<dim3(288, NEXP), 256, 0, stream>>>(w2 + (long)l * NEXP * HIDN * DM, w2f, HIDN, DM);

    mfma_gemm_kernel<DM, 1152, 0><<<dim3(25, 1, 18), 256, 0, stream>>>(
        t, wqf, qkv_b + l * 1152, nullptr, nullptr, qkv);
    attn_tile_kernel<<<dim3(BATCH * NHEAD, 7), 256, 0, stream>>>(qkv, attn);
    mfma_gemm_kernel<DM, DM, 0><<<dim3(25, 1, 6), 256, 0, stream>>>(
        attn, wpf, proj_b + l * DM, nullptr, nullptr, proj);
    add_ln_kernel<<<TOK, DM, 0, stream>>>(t, proj, ln1_g + l * DM, ln1_b + l * DM);

    prep_kernel<<<NEXP, DM, 0, stream>>>(b2 + l * NEXP * DM, bias0);
    bias0_partial_kernel<<<dim3(NEXP, 12), 384, 0, stream>>>(
        b1 + l * NEXP * HIDN, w2 + (long)l * NEXP * HIDN * DM, bias0);
    unsigned kl0, kl1;
    tf2x32(0u, 42u, 0u, (unsigned)l, kl0, kl1);
    router_logits_kernel<<<TOK / 4, 256, 0, stream>>>(
        t, router_w + l * DM * NEXP, router_b + l * NEXP, kl0, kl1, gates, idxb);
    bucket_kernel<<<1, 1024, 0, stream>>>(idxb, lists, counts, occ);
    bias_sum_kernel<<<2, 384, 0, stream>>>(bias0, occ, bias_sum);
    mfma_gemm_kernel<DM, HIDN, 1><<<dim3(25, NEXP, 24), 256, 0, stream>>>(
        t, w1f, b1 + l * NEXP * HIDN, lists, counts, hbuf);
    mfma_gemm_kernel<HIDN, DM, 2><<<dim3(25, NEXP, 6), 256, 0, stream>>>(
        hbuf, w2f, b2 + l * NEXP * DM, lists, counts, ybuf);
    moe_combine_ln_kernel<<<TOK, DM, 0, stream>>>(t, ybuf, gates, idxb, bias0, bias_sum,
                                                  ln2_g + l * DM, ln2_b + l * DM);
  }

  final_kernel<<<dim3(BATCH, 4), 256, 0, stream>>>(t, norm_g, norm_b, fc_w, fc_b,
                                                   (float*)d_out);
}